// Round 7
// baseline (511.796 us; speedup 1.0000x reference)
//
#include <hip/hip_runtime.h>

#define NN 20000
#define NPAD 20064  // >= 626*32 = 20032 rows covered by GEMM grid

typedef _Float16 half8 __attribute__((ext_vector_type(8)));
typedef _Float16 half2v __attribute__((ext_vector_type(2)));
typedef float floatx4 __attribute__((ext_vector_type(4)));

#define MFMA16(a, b, c) __builtin_amdgcn_mfma_f32_16x16x32_f16((a), (b), (c), 0, 0, 0)
#define LD8(p) (*(const half8*)(p))
#define SBAR() __builtin_amdgcn_sched_barrier(0)

// ---------------- B-spline basis (grid [-1,1], G=4, order 3, NB=7) ----------------
__device__ __forceinline__ void bspline7(float x, float b[7]) {
  float t[10];
#pragma unroll
  for (int i = 0; i < 10; ++i) {
    float g = -2.5f + 0.5f * (float)i;
    t[i] = (x >= g && x < g + 0.5f) ? 1.0f : 0.0f;
  }
#pragma unroll
  for (int i = 0; i < 9; ++i) {  // k=1, denom 0.5
    float g = -2.5f + 0.5f * (float)i;
    t[i] = ((x - g) * t[i] + (g + 1.0f - x) * t[i + 1]) * 2.0f;
  }
#pragma unroll
  for (int i = 0; i < 8; ++i) {  // k=2, denom 1.0
    float g = -2.5f + 0.5f * (float)i;
    t[i] = ((x - g) * t[i] + (g + 1.5f - x) * t[i + 1]);
  }
#pragma unroll
  for (int i = 0; i < 7; ++i) {  // k=3, denom 1.5
    float g = -2.5f + 0.5f * (float)i;
    b[i] = ((x - g) * t[i] + (g + 2.0f - x) * t[i + 1]) * (1.0f / 1.5f);
  }
}

__device__ __forceinline__ float silu_f(float x) {
  return x * (1.0f / (1.0f + __expf(-x)));
}

// ---------------- feature build: X (f32 row-major) -> F fp16 [row][i][j=0..7] ----------------
__global__ void fb_kernel(const float* __restrict__ X, const float* __restrict__ ss,
                          _Float16* __restrict__ F, int has_bn) {
  int idx = blockIdx.x * 256 + threadIdx.x;  // NN*128
  if (idx >= NN * 128) return;
  int c = idx & 127;
  float x = X[idx];
  if (has_bn) x = x * ss[c] + ss[128 + c];
  float b[7];
  bspline7(x, b);
  half8 hv;
  hv[0] = (_Float16)silu_f(x);
#pragma unroll
  for (int k = 0; k < 7; ++k) hv[k + 1] = (_Float16)b[k];
  *(half8*)(F + (size_t)idx * 8) = hv;
}

// ---------------- merged weight pack (MFMA B-fragment order) ----------------
__global__ void packw_all(const float* __restrict__ Wb0, const float* __restrict__ Ws0,
                          const float* __restrict__ Wb1, const float* __restrict__ Ws1,
                          const float* __restrict__ WbO, const float* __restrict__ WsO,
                          _Float16* __restrict__ WPA0, _Float16* __restrict__ WPA1,
                          _Float16* __restrict__ WPC) {
  int bid = blockIdx.x;
  if (bid < 1536) {
    int s = (bid >= 768) ? 1 : 0;
    int idx = (bid - s * 768) * 256 + threadIdx.x;  // 196608
    if (idx >= 196608) return;
    const float* Wb = s ? Wb1 : Wb0;
    const float* Wsp = s ? Ws1 : Ws0;
    _Float16* WP = s ? WPA1 : WPA0;
    int jj = idx & 7;
    int lane = (idx >> 3) & 63;
    int u = idx >> 9;  // ks*12 + cb
    int cb = u % 12, ks = u / 12;
    int i = ks * 4 + (lane >> 4);
    int orow = lane & 15;
    float v = 0.0f;
    if (cb < 8) {
      int o = cb * 16 + orow;
      v = (jj == 0) ? Wb[(size_t)o * 128 + i] : Wsp[(size_t)o * 896 + i * 7 + (jj - 1)];
    } else {
      int o = (cb - 8) * 16 + orow;
      if (o < 40)
        v = (jj == 0) ? WbO[(size_t)o * 384 + s * 128 + i]
                      : WsO[(size_t)o * 2688 + s * 896 + i * 7 + (jj - 1)];
    }
    WP[idx] = (_Float16)v;
  } else {
    int idx = (bid - 1536) * 256 + threadIdx.x;  // 65536
    if (idx >= 65536) return;
    int jj = idx & 7;
    int lane = (idx >> 3) & 63;
    int u = idx >> 9;
    int cb = u & 3, ks = u >> 2;
    int i = ks * 4 + (lane >> 4);
    int o = cb * 16 + (lane & 15);
    float v = 0.0f;
    if (o < 40)
      v = (jj == 0) ? WbO[(size_t)o * 384 + 2 * 128 + i]
                    : WsO[(size_t)o * 2688 + 2 * 896 + i * 7 + (jj - 1)];
    WPC[idx] = (_Float16)v;
  }
}

// ---------------- graph meta ----------------
__global__ void count_deg(const int* __restrict__ dst, int* __restrict__ degE, int E) {
  int e = blockIdx.x * 256 + threadIdx.x;
  if (e < E) atomicAdd(&degE[dst[e]], 1);
}

__global__ void build_meta2(const int* __restrict__ degE, int* __restrict__ rowptr,
                            int* __restrict__ cursor, float* __restrict__ dinv, int n) {
  __shared__ int wsum[16];
  int tid = threadIdx.x, lane = tid & 63, wid = tid >> 6;
  int i0 = tid * 20;
  int d[20];
  int s = 0;
#pragma unroll
  for (int j = 0; j < 20; ++j) {
    int i = i0 + j;
    int v = (i < n) ? degE[i] : 0;
    d[j] = v;
    s += v;
    if (i < n) dinv[i] = rsqrtf((float)(v + 1));  // +1 self loop
  }
  int val = s;
#pragma unroll
  for (int off = 1; off < 64; off <<= 1) {
    int t = __shfl_up(val, off);
    if (lane >= off) val += t;
  }
  if (lane == 63) wsum[wid] = val;
  __syncthreads();
  if (wid == 0) {
    int wv = (lane < 16) ? wsum[lane] : 0;
#pragma unroll
    for (int off = 1; off < 16; off <<= 1) {
      int t = __shfl_up(wv, off);
      if (lane >= off) wv += t;
    }
    if (lane < 16) wsum[lane] = wv;
  }
  __syncthreads();
  int base = (wid ? wsum[wid - 1] : 0) + val - s;
  if (tid == 0) rowptr[0] = 0;
#pragma unroll
  for (int j = 0; j < 20; ++j) {
    int i = i0 + j;
    if (i < n) {
      cursor[i] = base;
      rowptr[i + 1] = base + d[j];
      base += d[j];
    }
  }
}

__global__ void fill_csr(const int* __restrict__ src, const int* __restrict__ dst,
                         int* __restrict__ cursor, int* __restrict__ csr, int E) {
  int e = blockIdx.x * 256 + threadIdx.x;
  if (e < E) {
    int p = atomicAdd(&cursor[dst[e]], 1);
    csr[p] = src[e];
  }
}

// ---------------- GEMM A: 256 thr, wave = 32 rows x 3 cb, ping-pong depth-2 ----------------
__global__ __launch_bounds__(256) void gemmA5(const _Float16* __restrict__ F,
                                              const _Float16* __restrict__ WP,
                                              _Float16* __restrict__ A, float* __restrict__ P) {
  int lane = threadIdx.x & 63, cg = threadIdx.x >> 6;
  int row0 = blockIdx.x * 32;
  const _Float16* Fr0 = F + ((size_t)(row0 + (lane & 15)) * 128 + (lane >> 4)) * 8;
  const _Float16* Fr1 = Fr0 + 16 * 1024;
  const _Float16* Bp = WP + ((size_t)(cg * 3) * 64 + lane) * 8;
  floatx4 acc0 = {}, acc1 = {}, acc2 = {}, acc3 = {}, acc4 = {}, acc5 = {};
  // set X = even ks, set Y = odd ks (no rotation copies -> distinct registers)
  half8 xa0 = LD8(Fr0), xa1 = LD8(Fr1);
  half8 xb0 = LD8(Bp), xb1 = LD8(Bp + 512), xb2 = LD8(Bp + 1024);
  half8 ya0 = LD8(Fr0 + 32), ya1 = LD8(Fr1 + 32);
  half8 yb0 = LD8(Bp + 6144), yb1 = LD8(Bp + 6144 + 512), yb2 = LD8(Bp + 6144 + 1024);
#pragma unroll 1
  for (int ks = 0; ks < 32; ks += 2) {
    SBAR();
    acc0 = MFMA16(xa0, xb0, acc0);
    acc1 = MFMA16(xa0, xb1, acc1);
    acc2 = MFMA16(xa0, xb2, acc2);
    acc3 = MFMA16(xa1, xb0, acc3);
    acc4 = MFMA16(xa1, xb1, acc4);
    acc5 = MFMA16(xa1, xb2, acc5);
    SBAR();
    // load X for ks+2 (pads cover ks=32/33 overrun)
    xa0 = LD8(Fr0 + (size_t)(ks + 2) * 32);
    xa1 = LD8(Fr1 + (size_t)(ks + 2) * 32);
    {
      const _Float16* bn = Bp + (size_t)(ks + 2) * 6144;
      xb0 = LD8(bn); xb1 = LD8(bn + 512); xb2 = LD8(bn + 1024);
    }
    SBAR();
    acc0 = MFMA16(ya0, yb0, acc0);
    acc1 = MFMA16(ya0, yb1, acc1);
    acc2 = MFMA16(ya0, yb2, acc2);
    acc3 = MFMA16(ya1, yb0, acc3);
    acc4 = MFMA16(ya1, yb1, acc4);
    acc5 = MFMA16(ya1, yb2, acc5);
    SBAR();
    // load Y for ks+3
    ya0 = LD8(Fr0 + (size_t)(ks + 3) * 32);
    ya1 = LD8(Fr1 + (size_t)(ks + 3) * 32);
    {
      const _Float16* bn = Bp + (size_t)(ks + 3) * 6144;
      yb0 = LD8(bn); yb1 = LD8(bn + 512); yb2 = LD8(bn + 1024);
    }
    SBAR();
  }
  int oc = lane & 15;
  floatx4 accs[2][3] = {{acc0, acc1, acc2}, {acc3, acc4, acc5}};
#pragma unroll
  for (int rg = 0; rg < 2; ++rg) {
    int r0 = row0 + rg * 16 + (lane >> 4) * 4;
#pragma unroll
    for (int q = 0; q < 3; ++q) {
      int cb = cg * 3 + q;
      if (cb < 8) {
#pragma unroll
        for (int t = 0; t < 4; ++t)
          A[(size_t)(r0 + t) * 128 + cb * 16 + oc] = (_Float16)accs[rg][q][t];
      } else {
#pragma unroll
        for (int t = 0; t < 4; ++t) P[(size_t)(r0 + t) * 64 + (cb - 8) * 16 + oc] = accs[rg][q][t];
      }
    }
  }
}

// final chunk: F(h2 feats) x W_out_chunk2 + P0 + P1 -> C fp16; ping-pong depth-2
__global__ __launch_bounds__(256) void gemmC5(const _Float16* __restrict__ F,
                                              const _Float16* __restrict__ WP,
                                              const float* __restrict__ P0,
                                              const float* __restrict__ P1,
                                              _Float16* __restrict__ C) {
  int lane = threadIdx.x & 63, cg = threadIdx.x >> 6;
  int row0 = blockIdx.x * 32;
  const _Float16* Fr0 = F + ((size_t)(row0 + (lane & 15)) * 128 + (lane >> 4)) * 8;
  const _Float16* Fr1 = Fr0 + 16 * 1024;
  const _Float16* Bp = WP + ((size_t)cg * 64 + lane) * 8;
  floatx4 acc0 = {}, acc1 = {};
  half8 xa0 = LD8(Fr0), xa1 = LD8(Fr1), xb = LD8(Bp);
  half8 ya0 = LD8(Fr0 + 32), ya1 = LD8(Fr1 + 32), yb = LD8(Bp + 2048);
#pragma unroll 1
  for (int ks = 0; ks < 32; ks += 2) {
    SBAR();
    acc0 = MFMA16(xa0, xb, acc0);
    acc1 = MFMA16(xa1, xb, acc1);
    SBAR();
    xa0 = LD8(Fr0 + (size_t)(ks + 2) * 32);
    xa1 = LD8(Fr1 + (size_t)(ks + 2) * 32);
    xb = LD8(Bp + (size_t)(ks + 2) * 2048);
    SBAR();
    acc0 = MFMA16(ya0, yb, acc0);
    acc1 = MFMA16(ya1, yb, acc1);
    SBAR();
    ya0 = LD8(Fr0 + (size_t)(ks + 3) * 32);
    ya1 = LD8(Fr1 + (size_t)(ks + 3) * 32);
    yb = LD8(Bp + (size_t)(ks + 3) * 2048);
    SBAR();
  }
  int oc = lane & 15;
  floatx4 accs[2] = {acc0, acc1};
#pragma unroll
  for (int rg = 0; rg < 2; ++rg) {
    int r0 = row0 + rg * 16 + (lane >> 4) * 4;
#pragma unroll
    for (int t = 0; t < 4; ++t) {
      size_t idx = (size_t)(r0 + t) * 64 + cg * 16 + oc;
      C[idx] = (_Float16)(accs[rg][t] + P0[idx] + P1[idx]);
    }
  }
}

// ---------------- aggregation: wave per node, fp16 gather, depth-2 pipeline ----------------
__global__ __launch_bounds__(256) void aggregate128h(const _Float16* __restrict__ Ah,
                                                     const int* __restrict__ rowptr,
                                                     const int* __restrict__ csr,
                                                     const float* __restrict__ dinv,
                                                     const float* __restrict__ bias,
                                                     float* __restrict__ Y) {
  int wid = threadIdx.x >> 6, lane = threadIdx.x & 63;
  int n = blockIdx.x * 4 + wid;  // grid 5000 -> n < 20000
  float di = dinv[n];
  half2v self = *(const half2v*)(Ah + (size_t)n * 128 + lane * 2);
  float a0 = (float)self[0] * di, a1 = (float)self[1] * di;
  int e0 = rowptr[n], m = rowptr[n + 1] - e0;
  half2v r0 = {}, r1 = {};
  float d0 = 0.f, d1 = 0.f;
  if (m > 0) {
    int s0 = csr[e0];
    r0 = *(const half2v*)(Ah + (size_t)s0 * 128 + lane * 2);
    d0 = dinv[s0];
  }
  if (m > 1) {
    int s1 = csr[e0 + 1];
    r1 = *(const half2v*)(Ah + (size_t)s1 * 128 + lane * 2);
    d1 = dinv[s1];
  }
  for (int e = 0; e < m; ++e) {
    half2v r2 = {};
    float d2 = 0.f;
    if (e + 2 < m) {
      int s2 = csr[e0 + e + 2];
      r2 = *(const half2v*)(Ah + (size_t)s2 * 128 + lane * 2);
      d2 = dinv[s2];
    }
    a0 += (float)r0[0] * d0;
    a1 += (float)r0[1] * d0;
    r0 = r1; d0 = d1; r1 = r2; d1 = d2;
  }
  float2 outv = {a0 * di + bias[lane * 2], a1 * di + bias[lane * 2 + 1]};
  *(float2*)(Y + (size_t)n * 128 + lane * 2) = outv;
}

__global__ __launch_bounds__(256) void aggregate40h(const _Float16* __restrict__ Ch,
                                                    const int* __restrict__ rowptr,
                                                    const int* __restrict__ csr,
                                                    const float* __restrict__ dinv,
                                                    const float* __restrict__ bias,
                                                    float* __restrict__ out) {
  int wid = threadIdx.x >> 6, lane = threadIdx.x & 63;
  int n = blockIdx.x * 4 + wid;
  float di = dinv[n];
  float acc = (float)Ch[(size_t)n * 64 + lane] * di;
  int e0 = rowptr[n], m = rowptr[n + 1] - e0;
  float r0 = 0.f, r1 = 0.f, d0 = 0.f, d1 = 0.f;
  if (m > 0) {
    int s0 = csr[e0];
    r0 = (float)Ch[(size_t)s0 * 64 + lane];
    d0 = dinv[s0];
  }
  if (m > 1) {
    int s1 = csr[e0 + 1];
    r1 = (float)Ch[(size_t)s1 * 64 + lane];
    d1 = dinv[s1];
  }
  for (int e = 0; e < m; ++e) {
    float r2 = 0.f, d2 = 0.f;
    if (e + 2 < m) {
      int s2 = csr[e0 + e + 2];
      r2 = (float)Ch[(size_t)s2 * 64 + lane];
      d2 = dinv[s2];
    }
    acc += r0 * d0;
    r0 = r1; d0 = d1; r1 = r2; d1 = d2;
  }
  if (lane < 40) out[(size_t)n * 40 + lane] = acc * di + bias[lane];
}

// ---------------- batchnorm stats: 625 blocks x 32 rows, float4, 2-level reduce ----------------
__global__ __launch_bounds__(256) void bn_stats(const float* __restrict__ H,
                                                float* __restrict__ partial) {
  int tid = threadIdx.x;
  int c4 = (tid & 31) * 4;                     // column group
  int r0 = blockIdx.x * 32 + (tid >> 5) * 4;   // 4 rows per thread (grid 625 exact)
  float s0 = 0, s1 = 0, s2 = 0, s3 = 0, q0 = 0, q1 = 0, q2 = 0, q3 = 0;
#pragma unroll
  for (int j = 0; j < 4; ++j) {
    float4 v = *(const float4*)(H + (size_t)(r0 + j) * 128 + c4);
    s0 += v.x; s1 += v.y; s2 += v.z; s3 += v.w;
    q0 += v.x * v.x; q1 += v.y * v.y; q2 += v.z * v.z; q3 += v.w * v.w;
  }
  __shared__ float sh[2][256][4];  // 8 KB
  sh[0][tid][0] = s0; sh[0][tid][1] = s1; sh[0][tid][2] = s2; sh[0][tid][3] = s3;
  sh[1][tid][0] = q0; sh[1][tid][1] = q1; sh[1][tid][2] = q2; sh[1][tid][3] = q3;
  __syncthreads();
  if (tid < 32) {
    float a0 = 0, a1 = 0, a2 = 0, a3 = 0, b0 = 0, b1 = 0, b2 = 0, b3 = 0;
#pragma unroll
    for (int g = 0; g < 8; ++g) {
      int u = g * 32 + tid;
      a0 += sh[0][u][0]; a1 += sh[0][u][1]; a2 += sh[0][u][2]; a3 += sh[0][u][3];
      b0 += sh[1][u][0]; b1 += sh[1][u][1]; b2 += sh[1][u][2]; b3 += sh[1][u][3];
    }
    float* p = partial + (size_t)blockIdx.x * 256;
    p[tid * 4 + 0] = a0; p[tid * 4 + 1] = a1; p[tid * 4 + 2] = a2; p[tid * 4 + 3] = a3;
    p[128 + tid * 4 + 0] = b0; p[128 + tid * 4 + 1] = b1;
    p[128 + tid * 4 + 2] = b2; p[128 + tid * 4 + 3] = b3;
  }
}

__global__ __launch_bounds__(256) void bn_final(const float* __restrict__ partial,
                                                const float* __restrict__ gamma,
                                                const float* __restrict__ beta,
                                                float* __restrict__ ss) {
  int tid = threadIdx.x;  // 256 = 128 cols x 2 halves
  int c = tid & 127, h = tid >> 7;
  double s = 0.0, q = 0.0;
  for (int b = h; b < 625; b += 2) {
    s += (double)partial[(size_t)b * 256 + c];
    q += (double)partial[(size_t)b * 256 + 128 + c];
  }
  __shared__ double sh[512];
  sh[tid] = s;
  sh[256 + tid] = q;
  __syncthreads();
  if (tid < 128) {
    double S = sh[tid] + sh[tid + 128];
    double Q = sh[256 + tid] + sh[256 + tid + 128];
    double mean = S / (double)NN;
    double var = Q / (double)NN - mean * mean;
    float sc = gamma[tid] * rsqrtf((float)var + 1e-5f);
    ss[tid] = sc;
    ss[128 + tid] = beta[tid] - (float)mean * sc;
  }
}

// ---------------- launch ----------------
extern "C" void kernel_launch(void* const* d_in, const int* in_sizes, int n_in,
                              void* d_out, int out_size, void* d_ws, size_t ws_size,
                              hipStream_t stream) {
  const float* x = (const float*)d_in[0];
  const int* ei = (const int*)d_in[1];
  const float* bw0 = (const float*)d_in[2];
  const float* sw0 = (const float*)d_in[3];
  const float* b0 = (const float*)d_in[4];
  const float* bw1 = (const float*)d_in[5];
  const float* sw1 = (const float*)d_in[6];
  const float* b1 = (const float*)d_in[7];
  const float* bwo = (const float*)d_in[8];
  const float* swo = (const float*)d_in[9];
  const float* bo = (const float*)d_in[10];
  const float* gamma = (const float*)d_in[11];
  const float* beta = (const float*)d_in[12];
  const int E = in_sizes[1] / 2;
  const int* esrc = ei;
  const int* edst = ei + E;

  char* ws = (char*)d_ws;
  size_t off = 0;
  auto alloc = [&](size_t bytes) -> void* {
    void* p = ws + off;
    off = (off + bytes + 255) & ~(size_t)255;
    return p;
  };
  // weight packs padded for the ks+2/ks+3 prefetch overrun (up to 2 extra ks-steps)
  _Float16* WPA0 = (_Float16*)alloc((196608 + 16384) * 2);
  _Float16* WPA1 = (_Float16*)alloc((196608 + 16384) * 2);
  _Float16* WPC = (_Float16*)alloc((65536 + 16384) * 2);
  float* dinv = (float*)alloc(NN * 4);
  int* degE = (int*)alloc(NN * 4);
  int* rowptr = (int*)alloc((NN + 1) * 4);
  int* cursor = (int*)alloc(NN * 4);
  int* csr = (int*)alloc((size_t)E * 4);
  _Float16* F = (_Float16*)alloc(((size_t)NPAD * 1024 + 128) * 2);  // 41 MB, reused 3x
  _Float16* A = (_Float16*)alloc((size_t)NPAD * 128 * 2);           // fp16 GEMM out
  float* h1 = (float*)alloc((size_t)NN * 128 * 4);                  // h2 aliases h1
  float* P0 = (float*)alloc((size_t)NPAD * 64 * 4);
  float* P1 = (float*)alloc((size_t)NPAD * 64 * 4);
  _Float16* Ch = (_Float16*)alloc((size_t)NPAD * 64 * 2);           // fp16 combined out
  float* partial = (float*)alloc((size_t)625 * 256 * 4);
  float* ssb = (float*)alloc(256 * 4);
  float* h2 = h1;
  (void)ws_size; (void)n_in; (void)out_size;

  int egrid = (E + 255) / 256;
  const int GG = 626;  // 626*32 = 20032 rows

  hipMemsetAsync(degE, 0, NN * sizeof(int), stream);
  packw_all<<<1792, 256, 0, stream>>>(bw0, sw0, bw1, sw1, bwo, swo, WPA0, WPA1, WPC);
  count_deg<<<egrid, 256, 0, stream>>>(edst, degE, E);
  build_meta2<<<1, 1024, 0, stream>>>(degE, rowptr, cursor, dinv, NN);
  fill_csr<<<egrid, 256, 0, stream>>>(esrc, edst, cursor, csr, E);

  // layer 0 (+ out chunk 0)
  fb_kernel<<<10000, 256, 0, stream>>>(x, ssb, F, 0);
  gemmA5<<<GG, 256, 0, stream>>>(F, WPA0, A, P0);
  aggregate128h<<<5000, 256, 0, stream>>>(A, rowptr, csr, dinv, b0, h1);
  bn_stats<<<625, 256, 0, stream>>>(h1, partial);
  bn_final<<<1, 256, 0, stream>>>(partial, gamma, beta, ssb);

  // layer 1 (+ out chunk 1)
  fb_kernel<<<10000, 256, 0, stream>>>(h1, ssb, F, 1);
  gemmA5<<<GG, 256, 0, stream>>>(F, WPA1, A, P1);
  aggregate128h<<<5000, 256, 0, stream>>>(A, rowptr, csr, dinv, b1, h2);
  bn_stats<<<625, 256, 0, stream>>>(h2, partial);
  bn_final<<<1, 256, 0, stream>>>(partial, gamma, beta, ssb);

  // out chunk 2 + combine, then aggregate
  fb_kernel<<<10000, 256, 0, stream>>>(h2, ssb, F, 1);
  gemmC5<<<GG, 256, 0, stream>>>(F, WPC, P0, P1, Ch);
  aggregate40h<<<5000, 256, 0, stream>>>(Ch, rowptr, csr, dinv, bo, (float*)d_out);
}

// Round 8
// 343.906 us; speedup vs baseline: 1.4882x; 1.4882x over previous
//
#include <hip/hip_runtime.h>

#define NN 20000
#define NPAD 20064  // >= 626*32 = 20032 rows covered by GEMM grid

typedef _Float16 half8 __attribute__((ext_vector_type(8)));
typedef _Float16 half2v __attribute__((ext_vector_type(2)));
typedef float floatx4 __attribute__((ext_vector_type(4)));

#define MFMA16(a, b, c) __builtin_amdgcn_mfma_f32_16x16x32_f16((a), (b), (c), 0, 0, 0)
#define LD8(p) (*(const half8*)(p))
#define SBAR() __builtin_amdgcn_sched_barrier(0)

// ---------------- B-spline basis (grid [-1,1], G=4, order 3, NB=7) ----------------
__device__ __forceinline__ void bspline7(float x, float b[7]) {
  float t[10];
#pragma unroll
  for (int i = 0; i < 10; ++i) {
    float g = -2.5f + 0.5f * (float)i;
    t[i] = (x >= g && x < g + 0.5f) ? 1.0f : 0.0f;
  }
#pragma unroll
  for (int i = 0; i < 9; ++i) {  // k=1, denom 0.5
    float g = -2.5f + 0.5f * (float)i;
    t[i] = ((x - g) * t[i] + (g + 1.0f - x) * t[i + 1]) * 2.0f;
  }
#pragma unroll
  for (int i = 0; i < 8; ++i) {  // k=2, denom 1.0
    float g = -2.5f + 0.5f * (float)i;
    t[i] = ((x - g) * t[i] + (g + 1.5f - x) * t[i + 1]);
  }
#pragma unroll
  for (int i = 0; i < 7; ++i) {  // k=3, denom 1.5
    float g = -2.5f + 0.5f * (float)i;
    b[i] = ((x - g) * t[i] + (g + 2.0f - x) * t[i + 1]) * (1.0f / 1.5f);
  }
}

__device__ __forceinline__ float silu_f(float x) {
  return x * (1.0f / (1.0f + __expf(-x)));
}

// ---------------- feature build: X (f32 row-major) -> F fp16 [row][i][j=0..7] ----------------
__global__ void fb_kernel(const float* __restrict__ X, const float* __restrict__ ss,
                          _Float16* __restrict__ F, int has_bn) {
  int idx = blockIdx.x * 256 + threadIdx.x;  // NN*128
  if (idx >= NN * 128) return;
  int c = idx & 127;
  float x = X[idx];
  if (has_bn) x = x * ss[c] + ss[128 + c];
  float b[7];
  bspline7(x, b);
  half8 hv;
  hv[0] = (_Float16)silu_f(x);
#pragma unroll
  for (int k = 0; k < 7; ++k) hv[k + 1] = (_Float16)b[k];
  *(half8*)(F + (size_t)idx * 8) = hv;
}

// ---------------- merged weight pack (MFMA B-fragment order) ----------------
__global__ void packw_all(const float* __restrict__ Wb0, const float* __restrict__ Ws0,
                          const float* __restrict__ Wb1, const float* __restrict__ Ws1,
                          const float* __restrict__ WbO, const float* __restrict__ WsO,
                          _Float16* __restrict__ WPA0, _Float16* __restrict__ WPA1,
                          _Float16* __restrict__ WPC) {
  int bid = blockIdx.x;
  if (bid < 1536) {
    int s = (bid >= 768) ? 1 : 0;
    int idx = (bid - s * 768) * 256 + threadIdx.x;  // 196608
    if (idx >= 196608) return;
    const float* Wb = s ? Wb1 : Wb0;
    const float* Wsp = s ? Ws1 : Ws0;
    _Float16* WP = s ? WPA1 : WPA0;
    int jj = idx & 7;
    int lane = (idx >> 3) & 63;
    int u = idx >> 9;  // ks*12 + cb
    int cb = u % 12, ks = u / 12;
    int i = ks * 4 + (lane >> 4);
    int orow = lane & 15;
    float v = 0.0f;
    if (cb < 8) {
      int o = cb * 16 + orow;
      v = (jj == 0) ? Wb[(size_t)o * 128 + i] : Wsp[(size_t)o * 896 + i * 7 + (jj - 1)];
    } else {
      int o = (cb - 8) * 16 + orow;
      if (o < 40)
        v = (jj == 0) ? WbO[(size_t)o * 384 + s * 128 + i]
                      : WsO[(size_t)o * 2688 + s * 896 + i * 7 + (jj - 1)];
    }
    WP[idx] = (_Float16)v;
  } else {
    int idx = (bid - 1536) * 256 + threadIdx.x;  // 65536
    if (idx >= 65536) return;
    int jj = idx & 7;
    int lane = (idx >> 3) & 63;
    int u = idx >> 9;
    int cb = u & 3, ks = u >> 2;
    int i = ks * 4 + (lane >> 4);
    int o = cb * 16 + (lane & 15);
    float v = 0.0f;
    if (o < 40)
      v = (jj == 0) ? WbO[(size_t)o * 384 + 2 * 128 + i]
                    : WsO[(size_t)o * 2688 + 2 * 896 + i * 7 + (jj - 1)];
    WPC[idx] = (_Float16)v;
  }
}

// ---------------- graph meta ----------------
__global__ void count_deg(const int* __restrict__ dst, int* __restrict__ degE, int E) {
  int e = blockIdx.x * 256 + threadIdx.x;
  if (e < E) atomicAdd(&degE[dst[e]], 1);
}

__global__ void build_meta2(const int* __restrict__ degE, int* __restrict__ rowptr,
                            int* __restrict__ cursor, float* __restrict__ dinv, int n) {
  __shared__ int wsum[16];
  int tid = threadIdx.x, lane = tid & 63, wid = tid >> 6;
  int i0 = tid * 20;
  int d[20];
  int s = 0;
#pragma unroll
  for (int j = 0; j < 20; ++j) {
    int i = i0 + j;
    int v = (i < n) ? degE[i] : 0;
    d[j] = v;
    s += v;
    if (i < n) dinv[i] = rsqrtf((float)(v + 1));  // +1 self loop
  }
  int val = s;
#pragma unroll
  for (int off = 1; off < 64; off <<= 1) {
    int t = __shfl_up(val, off);
    if (lane >= off) val += t;
  }
  if (lane == 63) wsum[wid] = val;
  __syncthreads();
  if (wid == 0) {
    int wv = (lane < 16) ? wsum[lane] : 0;
#pragma unroll
    for (int off = 1; off < 16; off <<= 1) {
      int t = __shfl_up(wv, off);
      if (lane >= off) wv += t;
    }
    if (lane < 16) wsum[lane] = wv;
  }
  __syncthreads();
  int base = (wid ? wsum[wid - 1] : 0) + val - s;
  if (tid == 0) rowptr[0] = 0;
#pragma unroll
  for (int j = 0; j < 20; ++j) {
    int i = i0 + j;
    if (i < n) {
      cursor[i] = base;
      rowptr[i + 1] = base + d[j];
      base += d[j];
    }
  }
}

__global__ void fill_csr(const int* __restrict__ src, const int* __restrict__ dst,
                         int* __restrict__ cursor, int* __restrict__ csr, int E) {
  int e = blockIdx.x * 256 + threadIdx.x;
  if (e < E) {
    int p = atomicAdd(&cursor[dst[e]], 1);
    csr[p] = src[e];
  }
}

// ---------------- GEMM A: 256 thr, wave = 32 rows x 3 cb, ping-pong depth-2 ----------------
__global__ __launch_bounds__(256) void gemmA5(const _Float16* __restrict__ F,
                                              const _Float16* __restrict__ WP,
                                              _Float16* __restrict__ A, float* __restrict__ P) {
  int lane = threadIdx.x & 63, cg = threadIdx.x >> 6;
  int row0 = blockIdx.x * 32;
  const _Float16* Fr0 = F + ((size_t)(row0 + (lane & 15)) * 128 + (lane >> 4)) * 8;
  const _Float16* Fr1 = Fr0 + 16 * 1024;
  const _Float16* Bp = WP + ((size_t)(cg * 3) * 64 + lane) * 8;
  floatx4 acc0 = {}, acc1 = {}, acc2 = {}, acc3 = {}, acc4 = {}, acc5 = {};
  half8 xa0 = LD8(Fr0), xa1 = LD8(Fr1);
  half8 xb0 = LD8(Bp), xb1 = LD8(Bp + 512), xb2 = LD8(Bp + 1024);
  half8 ya0 = LD8(Fr0 + 32), ya1 = LD8(Fr1 + 32);
  half8 yb0 = LD8(Bp + 6144), yb1 = LD8(Bp + 6144 + 512), yb2 = LD8(Bp + 6144 + 1024);
#pragma unroll 1
  for (int ks = 0; ks < 32; ks += 2) {
    SBAR();
    acc0 = MFMA16(xa0, xb0, acc0);
    acc1 = MFMA16(xa0, xb1, acc1);
    acc2 = MFMA16(xa0, xb2, acc2);
    acc3 = MFMA16(xa1, xb0, acc3);
    acc4 = MFMA16(xa1, xb1, acc4);
    acc5 = MFMA16(xa1, xb2, acc5);
    SBAR();
    xa0 = LD8(Fr0 + (size_t)(ks + 2) * 32);
    xa1 = LD8(Fr1 + (size_t)(ks + 2) * 32);
    {
      const _Float16* bn = Bp + (size_t)(ks + 2) * 6144;
      xb0 = LD8(bn); xb1 = LD8(bn + 512); xb2 = LD8(bn + 1024);
    }
    SBAR();
    acc0 = MFMA16(ya0, yb0, acc0);
    acc1 = MFMA16(ya0, yb1, acc1);
    acc2 = MFMA16(ya0, yb2, acc2);
    acc3 = MFMA16(ya1, yb0, acc3);
    acc4 = MFMA16(ya1, yb1, acc4);
    acc5 = MFMA16(ya1, yb2, acc5);
    SBAR();
    ya0 = LD8(Fr0 + (size_t)(ks + 3) * 32);
    ya1 = LD8(Fr1 + (size_t)(ks + 3) * 32);
    {
      const _Float16* bn = Bp + (size_t)(ks + 3) * 6144;
      yb0 = LD8(bn); yb1 = LD8(bn + 512); yb2 = LD8(bn + 1024);
    }
    SBAR();
  }
  int oc = lane & 15;
  floatx4 accs[2][3] = {{acc0, acc1, acc2}, {acc3, acc4, acc5}};
#pragma unroll
  for (int rg = 0; rg < 2; ++rg) {
    int r0 = row0 + rg * 16 + (lane >> 4) * 4;
#pragma unroll
    for (int q = 0; q < 3; ++q) {
      int cb = cg * 3 + q;
      if (cb < 8) {
#pragma unroll
        for (int t = 0; t < 4; ++t)
          A[(size_t)(r0 + t) * 128 + cb * 16 + oc] = (_Float16)accs[rg][q][t];
      } else {
#pragma unroll
        for (int t = 0; t < 4; ++t) P[(size_t)(r0 + t) * 64 + (cb - 8) * 16 + oc] = accs[rg][q][t];
      }
    }
  }
}

// final chunk: F(h2 feats) x W_out_chunk2 + P0 + P1 -> C fp16; ping-pong depth-2
__global__ __launch_bounds__(256) void gemmC5(const _Float16* __restrict__ F,
                                              const _Float16* __restrict__ WP,
                                              const float* __restrict__ P0,
                                              const float* __restrict__ P1,
                                              _Float16* __restrict__ C) {
  int lane = threadIdx.x & 63, cg = threadIdx.x >> 6;
  int row0 = blockIdx.x * 32;
  const _Float16* Fr0 = F + ((size_t)(row0 + (lane & 15)) * 128 + (lane >> 4)) * 8;
  const _Float16* Fr1 = Fr0 + 16 * 1024;
  const _Float16* Bp = WP + ((size_t)cg * 64 + lane) * 8;
  floatx4 acc0 = {}, acc1 = {};
  half8 xa0 = LD8(Fr0), xa1 = LD8(Fr1), xb = LD8(Bp);
  half8 ya0 = LD8(Fr0 + 32), ya1 = LD8(Fr1 + 32), yb = LD8(Bp + 2048);
#pragma unroll 1
  for (int ks = 0; ks < 32; ks += 2) {
    SBAR();
    acc0 = MFMA16(xa0, xb, acc0);
    acc1 = MFMA16(xa1, xb, acc1);
    SBAR();
    xa0 = LD8(Fr0 + (size_t)(ks + 2) * 32);
    xa1 = LD8(Fr1 + (size_t)(ks + 2) * 32);
    xb = LD8(Bp + (size_t)(ks + 2) * 2048);
    SBAR();
    acc0 = MFMA16(ya0, yb, acc0);
    acc1 = MFMA16(ya1, yb, acc1);
    SBAR();
    ya0 = LD8(Fr0 + (size_t)(ks + 3) * 32);
    ya1 = LD8(Fr1 + (size_t)(ks + 3) * 32);
    yb = LD8(Bp + (size_t)(ks + 3) * 2048);
    SBAR();
  }
  int oc = lane & 15;
  floatx4 accs[2] = {acc0, acc1};
#pragma unroll
  for (int rg = 0; rg < 2; ++rg) {
    int r0 = row0 + rg * 16 + (lane >> 4) * 4;
#pragma unroll
    for (int t = 0; t < 4; ++t) {
      size_t idx = (size_t)(r0 + t) * 64 + cg * 16 + oc;
      C[idx] = (_Float16)(accs[rg][t] + P0[idx] + P1[idx]);
    }
  }
}

// ---------------- aggregation: wave per node, fp16 gather, depth-2 pipeline ----------------
__global__ __launch_bounds__(256) void aggregate128h(const _Float16* __restrict__ Ah,
                                                     const int* __restrict__ rowptr,
                                                     const int* __restrict__ csr,
                                                     const float* __restrict__ dinv,
                                                     const float* __restrict__ bias,
                                                     float* __restrict__ Y) {
  int wid = threadIdx.x >> 6, lane = threadIdx.x & 63;
  int n = blockIdx.x * 4 + wid;  // grid 5000 -> n < 20000
  float di = dinv[n];
  half2v self = *(const half2v*)(Ah + (size_t)n * 128 + lane * 2);
  float a0 = (float)self[0] * di, a1 = (float)self[1] * di;
  int e0 = rowptr[n], m = rowptr[n + 1] - e0;
  half2v r0 = {}, r1 = {};
  float d0 = 0.f, d1 = 0.f;
  if (m > 0) {
    int s0 = csr[e0];
    r0 = *(const half2v*)(Ah + (size_t)s0 * 128 + lane * 2);
    d0 = dinv[s0];
  }
  if (m > 1) {
    int s1 = csr[e0 + 1];
    r1 = *(const half2v*)(Ah + (size_t)s1 * 128 + lane * 2);
    d1 = dinv[s1];
  }
  for (int e = 0; e < m; ++e) {
    half2v r2 = {};
    float d2 = 0.f;
    if (e + 2 < m) {
      int s2 = csr[e0 + e + 2];
      r2 = *(const half2v*)(Ah + (size_t)s2 * 128 + lane * 2);
      d2 = dinv[s2];
    }
    a0 += (float)r0[0] * d0;
    a1 += (float)r0[1] * d0;
    r0 = r1; d0 = d1; r1 = r2; d1 = d2;
  }
  float2 outv = {a0 * di + bias[lane * 2], a1 * di + bias[lane * 2 + 1]};
  *(float2*)(Y + (size_t)n * 128 + lane * 2) = outv;
}

__global__ __launch_bounds__(256) void aggregate40h(const _Float16* __restrict__ Ch,
                                                    const int* __restrict__ rowptr,
                                                    const int* __restrict__ csr,
                                                    const float* __restrict__ dinv,
                                                    const float* __restrict__ bias,
                                                    float* __restrict__ out) {
  int wid = threadIdx.x >> 6, lane = threadIdx.x & 63;
  int n = blockIdx.x * 4 + wid;
  float di = dinv[n];
  float acc = (float)Ch[(size_t)n * 64 + lane] * di;
  int e0 = rowptr[n], m = rowptr[n + 1] - e0;
  float r0 = 0.f, r1 = 0.f, d0 = 0.f, d1 = 0.f;
  if (m > 0) {
    int s0 = csr[e0];
    r0 = (float)Ch[(size_t)s0 * 64 + lane];
    d0 = dinv[s0];
  }
  if (m > 1) {
    int s1 = csr[e0 + 1];
    r1 = (float)Ch[(size_t)s1 * 64 + lane];
    d1 = dinv[s1];
  }
  for (int e = 0; e < m; ++e) {
    float r2 = 0.f, d2 = 0.f;
    if (e + 2 < m) {
      int s2 = csr[e0 + e + 2];
      r2 = (float)Ch[(size_t)s2 * 64 + lane];
      d2 = dinv[s2];
    }
    acc += r0 * d0;
    r0 = r1; d0 = d1; r1 = r2; d1 = d2;
  }
  if (lane < 40) out[(size_t)n * 40 + lane] = acc * di + bias[lane];
}

// ---------------- batchnorm: 3-stage deterministic tree ----------------
__global__ __launch_bounds__(256) void bn_stats(const float* __restrict__ H,
                                                float* __restrict__ partial) {
  int tid = threadIdx.x;
  int c4 = (tid & 31) * 4;                     // column group
  int r0 = blockIdx.x * 32 + (tid >> 5) * 4;   // 4 rows per thread (grid 625 exact)
  float s0 = 0, s1 = 0, s2 = 0, s3 = 0, q0 = 0, q1 = 0, q2 = 0, q3 = 0;
#pragma unroll
  for (int j = 0; j < 4; ++j) {
    float4 v = *(const float4*)(H + (size_t)(r0 + j) * 128 + c4);
    s0 += v.x; s1 += v.y; s2 += v.z; s3 += v.w;
    q0 += v.x * v.x; q1 += v.y * v.y; q2 += v.z * v.z; q3 += v.w * v.w;
  }
  __shared__ float sh[2][256][4];  // 8 KB
  sh[0][tid][0] = s0; sh[0][tid][1] = s1; sh[0][tid][2] = s2; sh[0][tid][3] = s3;
  sh[1][tid][0] = q0; sh[1][tid][1] = q1; sh[1][tid][2] = q2; sh[1][tid][3] = q3;
  __syncthreads();
  if (tid < 32) {
    float a0 = 0, a1 = 0, a2 = 0, a3 = 0, b0 = 0, b1 = 0, b2 = 0, b3 = 0;
#pragma unroll
    for (int g = 0; g < 8; ++g) {
      int u = g * 32 + tid;
      a0 += sh[0][u][0]; a1 += sh[0][u][1]; a2 += sh[0][u][2]; a3 += sh[0][u][3];
      b0 += sh[1][u][0]; b1 += sh[1][u][1]; b2 += sh[1][u][2]; b3 += sh[1][u][3];
    }
    float* p = partial + (size_t)blockIdx.x * 256;
    p[tid * 4 + 0] = a0; p[tid * 4 + 1] = a1; p[tid * 4 + 2] = a2; p[tid * 4 + 3] = a3;
    p[128 + tid * 4 + 0] = b0; p[128 + tid * 4 + 1] = b1;
    p[128 + tid * 4 + 2] = b2; p[128 + tid * 4 + 3] = b3;
  }
}

// 25 blocks x 256 thr: block b sums partial rows [25b, 25b+25) col tid -> p2[b*256+tid].
// 5 independent accumulators keep 5 loads in flight (fixed order -> deterministic).
__global__ __launch_bounds__(256) void bn_reduce(const float* __restrict__ partial,
                                                 float* __restrict__ p2) {
  int tid = threadIdx.x;
  const float* base = partial + (size_t)blockIdx.x * 25 * 256 + tid;
  float a0 = 0, a1 = 0, a2 = 0, a3 = 0, a4 = 0;
#pragma unroll
  for (int j = 0; j < 5; ++j) {
    a0 += base[(j * 5 + 0) * 256];
    a1 += base[(j * 5 + 1) * 256];
    a2 += base[(j * 5 + 2) * 256];
    a3 += base[(j * 5 + 3) * 256];
    a4 += base[(j * 5 + 4) * 256];
  }
  p2[(size_t)blockIdx.x * 256 + tid] = ((a0 + a1) + (a2 + a3)) + a4;
}

// 1 block: 25 rows only; 5 independent f64 accumulators.
__global__ __launch_bounds__(256) void bn_final2(const float* __restrict__ p2,
                                                 const float* __restrict__ gamma,
                                                 const float* __restrict__ beta,
                                                 float* __restrict__ ss) {
  int tid = threadIdx.x;  // col index into 256-wide [sum|sq] layout
  double a0 = 0, a1 = 0, a2 = 0, a3 = 0, a4 = 0;
#pragma unroll
  for (int j = 0; j < 5; ++j) {
    a0 += (double)p2[(size_t)(j * 5 + 0) * 256 + tid];
    a1 += (double)p2[(size_t)(j * 5 + 1) * 256 + tid];
    a2 += (double)p2[(size_t)(j * 5 + 2) * 256 + tid];
    a3 += (double)p2[(size_t)(j * 5 + 3) * 256 + tid];
    a4 += (double)p2[(size_t)(j * 5 + 4) * 256 + tid];
  }
  double tot = ((a0 + a1) + (a2 + a3)) + a4;
  __shared__ double sh[256];
  sh[tid] = tot;
  __syncthreads();
  if (tid < 128) {
    double S = sh[tid];
    double Q = sh[128 + tid];
    double mean = S / (double)NN;
    double var = Q / (double)NN - mean * mean;
    float sc = gamma[tid] * rsqrtf((float)var + 1e-5f);
    ss[tid] = sc;
    ss[128 + tid] = beta[tid] - (float)mean * sc;
  }
}

// ---------------- launch ----------------
extern "C" void kernel_launch(void* const* d_in, const int* in_sizes, int n_in,
                              void* d_out, int out_size, void* d_ws, size_t ws_size,
                              hipStream_t stream) {
  const float* x = (const float*)d_in[0];
  const int* ei = (const int*)d_in[1];
  const float* bw0 = (const float*)d_in[2];
  const float* sw0 = (const float*)d_in[3];
  const float* b0 = (const float*)d_in[4];
  const float* bw1 = (const float*)d_in[5];
  const float* sw1 = (const float*)d_in[6];
  const float* b1 = (const float*)d_in[7];
  const float* bwo = (const float*)d_in[8];
  const float* swo = (const float*)d_in[9];
  const float* bo = (const float*)d_in[10];
  const float* gamma = (const float*)d_in[11];
  const float* beta = (const float*)d_in[12];
  const int E = in_sizes[1] / 2;
  const int* esrc = ei;
  const int* edst = ei + E;

  char* ws = (char*)d_ws;
  size_t off = 0;
  auto alloc = [&](size_t bytes) -> void* {
    void* p = ws + off;
    off = (off + bytes + 255) & ~(size_t)255;
    return p;
  };
  // weight packs padded for the ks+2/ks+3 prefetch overrun (up to 2 extra ks-steps)
  _Float16* WPA0 = (_Float16*)alloc((196608 + 16384) * 2);
  _Float16* WPA1 = (_Float16*)alloc((196608 + 16384) * 2);
  _Float16* WPC = (_Float16*)alloc((65536 + 16384) * 2);
  float* dinv = (float*)alloc(NN * 4);
  int* degE = (int*)alloc(NN * 4);
  int* rowptr = (int*)alloc((NN + 1) * 4);
  int* cursor = (int*)alloc(NN * 4);
  int* csr = (int*)alloc((size_t)E * 4);
  _Float16* F = (_Float16*)alloc(((size_t)NPAD * 1024 + 128) * 2);  // 41 MB, reused 3x
  _Float16* A = (_Float16*)alloc((size_t)NPAD * 128 * 2);           // fp16 GEMM out
  float* h1 = (float*)alloc((size_t)NN * 128 * 4);                  // h2 aliases h1
  float* P0 = (float*)alloc((size_t)NPAD * 64 * 4);
  float* P1 = (float*)alloc((size_t)NPAD * 64 * 4);
  _Float16* Ch = (_Float16*)alloc((size_t)NPAD * 64 * 2);           // fp16 combined out
  float* partial = (float*)alloc((size_t)625 * 256 * 4);
  float* p2 = (float*)alloc((size_t)25 * 256 * 4);
  float* ssb = (float*)alloc(256 * 4);
  float* h2 = h1;
  (void)ws_size; (void)n_in; (void)out_size;

  int egrid = (E + 255) / 256;
  const int GG = 626;  // 626*32 = 20032 rows

  hipMemsetAsync(degE, 0, NN * sizeof(int), stream);
  packw_all<<<1792, 256, 0, stream>>>(bw0, sw0, bw1, sw1, bwo, swo, WPA0, WPA1, WPC);
  count_deg<<<egrid, 256, 0, stream>>>(edst, degE, E);
  build_meta2<<<1, 1024, 0, stream>>>(degE, rowptr, cursor, dinv, NN);
  fill_csr<<<egrid, 256, 0, stream>>>(esrc, edst, cursor, csr, E);

  // layer 0 (+ out chunk 0)
  fb_kernel<<<10000, 256, 0, stream>>>(x, ssb, F, 0);
  gemmA5<<<GG, 256, 0, stream>>>(F, WPA0, A, P0);
  aggregate128h<<<5000, 256, 0, stream>>>(A, rowptr, csr, dinv, b0, h1);
  bn_stats<<<625, 256, 0, stream>>>(h1, partial);
  bn_reduce<<<25, 256, 0, stream>>>(partial, p2);
  bn_final2<<<1, 256, 0, stream>>>(p2, gamma, beta, ssb);

  // layer 1 (+ out chunk 1)
  fb_kernel<<<10000, 256, 0, stream>>>(h1, ssb, F, 1);
  gemmA5<<<GG, 256, 0, stream>>>(F, WPA1, A, P1);
  aggregate128h<<<5000, 256, 0, stream>>>(A, rowptr, csr, dinv, b1, h2);
  bn_stats<<<625, 256, 0, stream>>>(h2, partial);
  bn_reduce<<<25, 256, 0, stream>>>(partial, p2);
  bn_final2<<<1, 256, 0, stream>>>(p2, gamma, beta, ssb);

  // out chunk 2 + combine, then aggregate
  fb_kernel<<<10000, 256, 0, stream>>>(h2, ssb, F, 1);
  gemmC5<<<GG, 256, 0, stream>>>(F, WPC, P0, P1, Ch);
  aggregate40h<<<5000, 256, 0, stream>>>(Ch, rowptr, csr, dinv, bo, (float*)d_out);
}

// Round 9
// 250.007 us; speedup vs baseline: 2.0471x; 1.3756x over previous
//
#include <hip/hip_runtime.h>

#define NN 20000
#define NPAD 20064  // >= 626*32 = 20032 rows covered by GEMM grid

typedef _Float16 half8 __attribute__((ext_vector_type(8)));
typedef _Float16 half2v __attribute__((ext_vector_type(2)));
typedef float floatx4 __attribute__((ext_vector_type(4)));

#define MFMA16(a, b, c) __builtin_amdgcn_mfma_f32_16x16x32_f16((a), (b), (c), 0, 0, 0)
#define LD8(p) (*(const half8*)(p))
#define SBAR() __builtin_amdgcn_sched_barrier(0)

// ---------------- B-spline basis (grid [-1,1], G=4, order 3, NB=7) ----------------
__device__ __forceinline__ void bspline7(float x, float b[7]) {
  float t[10];
#pragma unroll
  for (int i = 0; i < 10; ++i) {
    float g = -2.5f + 0.5f * (float)i;
    t[i] = (x >= g && x < g + 0.5f) ? 1.0f : 0.0f;
  }
#pragma unroll
  for (int i = 0; i < 9; ++i) {  // k=1, denom 0.5
    float g = -2.5f + 0.5f * (float)i;
    t[i] = ((x - g) * t[i] + (g + 1.0f - x) * t[i + 1]) * 2.0f;
  }
#pragma unroll
  for (int i = 0; i < 8; ++i) {  // k=2, denom 1.0
    float g = -2.5f + 0.5f * (float)i;
    t[i] = ((x - g) * t[i] + (g + 1.5f - x) * t[i + 1]);
  }
#pragma unroll
  for (int i = 0; i < 7; ++i) {  // k=3, denom 1.5
    float g = -2.5f + 0.5f * (float)i;
    b[i] = ((x - g) * t[i] + (g + 2.0f - x) * t[i + 1]) * (1.0f / 1.5f);
  }
}

__device__ __forceinline__ float silu_f(float x) {
  return x * (1.0f / (1.0f + __expf(-x)));
}

// Build 32 rows of fp16 features into LDS. Layout: Fs[r][chunk][j] with chunk = i ^ (r&7)
// (round-2 verified swizzle). Optional BN applied inline. OOB rows -> x=0.
__device__ __forceinline__ void build_lds(const float* __restrict__ X,
                                          const float* __restrict__ ss, int has_bn,
                                          int row0, int tid, _Float16* __restrict__ Fs) {
  for (int idx = tid; idx < 32 * 128; idx += 256) {
    int r = idx >> 7, i = idx & 127;
    int row = row0 + r;
    float xv = (row < NN) ? X[(size_t)row * 128 + i] : 0.0f;
    if (has_bn) xv = xv * ss[i] + ss[128 + i];
    float b[7];
    bspline7(xv, b);
    half8 hv;
    hv[0] = (_Float16)silu_f(xv);
#pragma unroll
    for (int k = 0; k < 7; ++k) hv[k + 1] = (_Float16)b[k];
    *(half8*)(Fs + ((size_t)r * 128 + (i ^ (r & 7))) * 8) = hv;
  }
}

// ---------------- merged weight pack (MFMA B-fragment order) ----------------
__global__ void packw_all(const float* __restrict__ Wb0, const float* __restrict__ Ws0,
                          const float* __restrict__ Wb1, const float* __restrict__ Ws1,
                          const float* __restrict__ WbO, const float* __restrict__ WsO,
                          _Float16* __restrict__ WPA0, _Float16* __restrict__ WPA1,
                          _Float16* __restrict__ WPC) {
  int bid = blockIdx.x;
  if (bid < 1536) {
    int s = (bid >= 768) ? 1 : 0;
    int idx = (bid - s * 768) * 256 + threadIdx.x;  // 196608
    if (idx >= 196608) return;
    const float* Wb = s ? Wb1 : Wb0;
    const float* Wsp = s ? Ws1 : Ws0;
    _Float16* WP = s ? WPA1 : WPA0;
    int jj = idx & 7;
    int lane = (idx >> 3) & 63;
    int u = idx >> 9;  // ks*12 + cb
    int cb = u % 12, ks = u / 12;
    int i = ks * 4 + (lane >> 4);
    int orow = lane & 15;
    float v = 0.0f;
    if (cb < 8) {
      int o = cb * 16 + orow;
      v = (jj == 0) ? Wb[(size_t)o * 128 + i] : Wsp[(size_t)o * 896 + i * 7 + (jj - 1)];
    } else {
      int o = (cb - 8) * 16 + orow;
      if (o < 40)
        v = (jj == 0) ? WbO[(size_t)o * 384 + s * 128 + i]
                      : WsO[(size_t)o * 2688 + s * 896 + i * 7 + (jj - 1)];
    }
    WP[idx] = (_Float16)v;
  } else {
    int idx = (bid - 1536) * 256 + threadIdx.x;  // 65536
    if (idx >= 65536) return;
    int jj = idx & 7;
    int lane = (idx >> 3) & 63;
    int u = idx >> 9;
    int cb = u & 3, ks = u >> 2;
    int i = ks * 4 + (lane >> 4);
    int o = cb * 16 + (lane & 15);
    float v = 0.0f;
    if (o < 40)
      v = (jj == 0) ? WbO[(size_t)o * 384 + 2 * 128 + i]
                    : WsO[(size_t)o * 2688 + 2 * 896 + i * 7 + (jj - 1)];
    WPC[idx] = (_Float16)v;
  }
}

// ---------------- graph meta ----------------
__global__ void count_deg(const int* __restrict__ dst, int* __restrict__ degE, int E) {
  int e = blockIdx.x * 256 + threadIdx.x;
  if (e < E) atomicAdd(&degE[dst[e]], 1);
}

__global__ void build_meta2(const int* __restrict__ degE, int* __restrict__ rowptr,
                            int* __restrict__ cursor, float* __restrict__ dinv, int n) {
  __shared__ int wsum[16];
  int tid = threadIdx.x, lane = tid & 63, wid = tid >> 6;
  int i0 = tid * 20;
  int d[20];
  int s = 0;
#pragma unroll
  for (int j = 0; j < 20; ++j) {
    int i = i0 + j;
    int v = (i < n) ? degE[i] : 0;
    d[j] = v;
    s += v;
    if (i < n) dinv[i] = rsqrtf((float)(v + 1));  // +1 self loop
  }
  int val = s;
#pragma unroll
  for (int off = 1; off < 64; off <<= 1) {
    int t = __shfl_up(val, off);
    if (lane >= off) val += t;
  }
  if (lane == 63) wsum[wid] = val;
  __syncthreads();
  if (wid == 0) {
    int wv = (lane < 16) ? wsum[lane] : 0;
#pragma unroll
    for (int off = 1; off < 16; off <<= 1) {
      int t = __shfl_up(wv, off);
      if (lane >= off) wv += t;
    }
    if (lane < 16) wsum[lane] = wv;
  }
  __syncthreads();
  int base = (wid ? wsum[wid - 1] : 0) + val - s;
  if (tid == 0) rowptr[0] = 0;
#pragma unroll
  for (int j = 0; j < 20; ++j) {
    int i = i0 + j;
    if (i < n) {
      cursor[i] = base;
      rowptr[i + 1] = base + d[j];
      base += d[j];
    }
  }
}

__global__ void fill_csr(const int* __restrict__ src, const int* __restrict__ dst,
                         int* __restrict__ cursor, int* __restrict__ csr, int E) {
  int e = blockIdx.x * 256 + threadIdx.x;
  if (e < E) {
    int p = atomicAdd(&cursor[dst[e]], 1);
    csr[p] = src[e];
  }
}

// ---------------- fused KAN GEMM: build features in LDS + MFMA ----------------
// 256 thr = 4 waves; wave = 32 rows x 3 cb (cg=wid). A from LDS, B global ping-pong depth-2.
// Outputs: A' = acc*dinv[row] fp16 (layer cols), P = acc f32 (out-chunk cols).
__global__ __launch_bounds__(256) void gemmFA(const float* __restrict__ X,
                                              const float* __restrict__ ss, int has_bn,
                                              const _Float16* __restrict__ WP,
                                              const float* __restrict__ dinv,
                                              _Float16* __restrict__ A, float* __restrict__ P) {
  __shared__ _Float16 Fs[32 * 1024];  // 64 KB
  int tid = threadIdx.x;
  int lane = tid & 63, cg = tid >> 6;
  int row0 = blockIdx.x * 32;
  build_lds(X, ss, has_bn, row0, tid, Fs);
  __syncthreads();
  int rx = lane & 7, kg = lane >> 4;
  const _Float16* Fr0 = Fs + (size_t)(lane & 15) * 1024;
  const _Float16* Fr1 = Fr0 + 16 * 1024;
  const _Float16* Bp = WP + ((size_t)(cg * 3) * 64 + lane) * 8;
  floatx4 acc0 = {}, acc1 = {}, acc2 = {}, acc3 = {}, acc4 = {}, acc5 = {};
  half8 xb0 = LD8(Bp), xb1 = LD8(Bp + 512), xb2 = LD8(Bp + 1024);
  half8 yb0 = LD8(Bp + 6144), yb1 = LD8(Bp + 6144 + 512), yb2 = LD8(Bp + 6144 + 1024);
#pragma unroll 1
  for (int ks = 0; ks < 32; ks += 2) {
    half8 a0 = LD8(Fr0 + (size_t)((ks * 4 + kg) ^ rx) * 8);
    half8 a1 = LD8(Fr1 + (size_t)((ks * 4 + kg) ^ rx) * 8);
    SBAR();
    acc0 = MFMA16(a0, xb0, acc0);
    acc1 = MFMA16(a0, xb1, acc1);
    acc2 = MFMA16(a0, xb2, acc2);
    acc3 = MFMA16(a1, xb0, acc3);
    acc4 = MFMA16(a1, xb1, acc4);
    acc5 = MFMA16(a1, xb2, acc5);
    SBAR();
    {  // B for ks+2 (pad covers overrun)
      const _Float16* bn = Bp + (size_t)(ks + 2) * 6144;
      xb0 = LD8(bn); xb1 = LD8(bn + 512); xb2 = LD8(bn + 1024);
    }
    half8 c0 = LD8(Fr0 + (size_t)(((ks + 1) * 4 + kg) ^ rx) * 8);
    half8 c1 = LD8(Fr1 + (size_t)(((ks + 1) * 4 + kg) ^ rx) * 8);
    SBAR();
    acc0 = MFMA16(c0, yb0, acc0);
    acc1 = MFMA16(c0, yb1, acc1);
    acc2 = MFMA16(c0, yb2, acc2);
    acc3 = MFMA16(c1, yb0, acc3);
    acc4 = MFMA16(c1, yb1, acc4);
    acc5 = MFMA16(c1, yb2, acc5);
    SBAR();
    {  // B for ks+3
      const _Float16* bn = Bp + (size_t)(ks + 3) * 6144;
      yb0 = LD8(bn); yb1 = LD8(bn + 512); yb2 = LD8(bn + 1024);
    }
    SBAR();
  }
  int oc = lane & 15;
  floatx4 accs[2][3] = {{acc0, acc1, acc2}, {acc3, acc4, acc5}};
#pragma unroll
  for (int rg = 0; rg < 2; ++rg) {
    int r0 = row0 + rg * 16 + (lane >> 4) * 4;
#pragma unroll
    for (int q = 0; q < 3; ++q) {
      int cb = cg * 3 + q;
      if (cb < 8) {
#pragma unroll
        for (int t = 0; t < 4; ++t)
          A[(size_t)(r0 + t) * 128 + cb * 16 + oc] = (_Float16)(accs[rg][q][t] * dinv[r0 + t]);
      } else {
#pragma unroll
        for (int t = 0; t < 4; ++t) P[(size_t)(r0 + t) * 64 + (cb - 8) * 16 + oc] = accs[rg][q][t];
      }
    }
  }
}

// fused final chunk: build(h2) + GEMM (4 cb) + P0 + P1, scaled by dinv -> C fp16
__global__ __launch_bounds__(256) void gemmFC(const float* __restrict__ X,
                                              const float* __restrict__ ss,
                                              const _Float16* __restrict__ WP,
                                              const float* __restrict__ P0,
                                              const float* __restrict__ P1,
                                              const float* __restrict__ dinv,
                                              _Float16* __restrict__ C) {
  __shared__ _Float16 Fs[32 * 1024];  // 64 KB
  int tid = threadIdx.x;
  int lane = tid & 63, cg = tid >> 6;
  int row0 = blockIdx.x * 32;
  build_lds(X, ss, 1, row0, tid, Fs);
  __syncthreads();
  int rx = lane & 7, kg = lane >> 4;
  const _Float16* Fr0 = Fs + (size_t)(lane & 15) * 1024;
  const _Float16* Fr1 = Fr0 + 16 * 1024;
  const _Float16* Bp = WP + ((size_t)cg * 64 + lane) * 8;
  floatx4 acc0 = {}, acc1 = {};
  half8 xb = LD8(Bp), yb = LD8(Bp + 2048);
#pragma unroll 1
  for (int ks = 0; ks < 32; ks += 2) {
    half8 a0 = LD8(Fr0 + (size_t)((ks * 4 + kg) ^ rx) * 8);
    half8 a1 = LD8(Fr1 + (size_t)((ks * 4 + kg) ^ rx) * 8);
    SBAR();
    acc0 = MFMA16(a0, xb, acc0);
    acc1 = MFMA16(a1, xb, acc1);
    SBAR();
    xb = LD8(Bp + (size_t)(ks + 2) * 2048);
    half8 c0 = LD8(Fr0 + (size_t)(((ks + 1) * 4 + kg) ^ rx) * 8);
    half8 c1 = LD8(Fr1 + (size_t)(((ks + 1) * 4 + kg) ^ rx) * 8);
    SBAR();
    acc0 = MFMA16(c0, yb, acc0);
    acc1 = MFMA16(c1, yb, acc1);
    SBAR();
    yb = LD8(Bp + (size_t)(ks + 3) * 2048);
    SBAR();
  }
  int oc = lane & 15;
  floatx4 accs[2] = {acc0, acc1};
#pragma unroll
  for (int rg = 0; rg < 2; ++rg) {
    int r0 = row0 + rg * 16 + (lane >> 4) * 4;
#pragma unroll
    for (int t = 0; t < 4; ++t) {
      size_t idx = (size_t)(r0 + t) * 64 + cg * 16 + oc;
      C[idx] = (_Float16)((accs[rg][t] + P0[idx] + P1[idx]) * dinv[r0 + t]);
    }
  }
}

// ---------------- aggregation: wave per node, pre-scaled fp16 rows, 4-way ILP ----------------
__global__ __launch_bounds__(256) void aggregate128h(const _Float16* __restrict__ Ah,
                                                     const int* __restrict__ rowptr,
                                                     const int* __restrict__ csr,
                                                     const float* __restrict__ dinv,
                                                     const float* __restrict__ bias,
                                                     float* __restrict__ Y) {
  int wid = threadIdx.x >> 6, lane = threadIdx.x & 63;
  int n = blockIdx.x * 4 + wid;  // grid 5000 -> n < 20000
  float di = dinv[n];
  half2v self = *(const half2v*)(Ah + (size_t)n * 128 + lane * 2);
  float a0 = (float)self[0], a1 = (float)self[1];
  float b0x = 0, b0y = 0, b1x = 0, b1y = 0, b2x = 0, b2y = 0, b3x = 0, b3y = 0;
  int e0 = rowptr[n], m = rowptr[n + 1] - e0;
  int j = 0;
  for (; j + 4 <= m; j += 4) {
    int s0 = csr[e0 + j], s1 = csr[e0 + j + 1], s2 = csr[e0 + j + 2], s3 = csr[e0 + j + 3];
    half2v r0 = *(const half2v*)(Ah + (size_t)s0 * 128 + lane * 2);
    half2v r1 = *(const half2v*)(Ah + (size_t)s1 * 128 + lane * 2);
    half2v r2 = *(const half2v*)(Ah + (size_t)s2 * 128 + lane * 2);
    half2v r3 = *(const half2v*)(Ah + (size_t)s3 * 128 + lane * 2);
    b0x += (float)r0[0]; b0y += (float)r0[1];
    b1x += (float)r1[0]; b1y += (float)r1[1];
    b2x += (float)r2[0]; b2y += (float)r2[1];
    b3x += (float)r3[0]; b3y += (float)r3[1];
  }
  for (; j < m; ++j) {
    int s = csr[e0 + j];
    half2v r = *(const half2v*)(Ah + (size_t)s * 128 + lane * 2);
    b0x += (float)r[0]; b0y += (float)r[1];
  }
  a0 += (b0x + b1x) + (b2x + b3x);
  a1 += (b0y + b1y) + (b2y + b3y);
  float2 outv = {a0 * di + bias[lane * 2], a1 * di + bias[lane * 2 + 1]};
  *(float2*)(Y + (size_t)n * 128 + lane * 2) = outv;
}

__global__ __launch_bounds__(256) void aggregate40h(const _Float16* __restrict__ Ch,
                                                    const int* __restrict__ rowptr,
                                                    const int* __restrict__ csr,
                                                    const float* __restrict__ dinv,
                                                    const float* __restrict__ bias,
                                                    float* __restrict__ out) {
  int wid = threadIdx.x >> 6, lane = threadIdx.x & 63;
  int n = blockIdx.x * 4 + wid;
  float di = dinv[n];
  float a = (float)Ch[(size_t)n * 64 + lane];
  float b0 = 0, b1 = 0, b2 = 0, b3 = 0;
  int e0 = rowptr[n], m = rowptr[n + 1] - e0;
  int j = 0;
  for (; j + 4 <= m; j += 4) {
    int s0 = csr[e0 + j], s1 = csr[e0 + j + 1], s2 = csr[e0 + j + 2], s3 = csr[e0 + j + 3];
    b0 += (float)Ch[(size_t)s0 * 64 + lane];
    b1 += (float)Ch[(size_t)s1 * 64 + lane];
    b2 += (float)Ch[(size_t)s2 * 64 + lane];
    b3 += (float)Ch[(size_t)s3 * 64 + lane];
  }
  for (; j < m; ++j) {
    int s = csr[e0 + j];
    b0 += (float)Ch[(size_t)s * 64 + lane];
  }
  a += (b0 + b1) + (b2 + b3);
  if (lane < 40) out[(size_t)n * 40 + lane] = a * di + bias[lane];
}

// ---------------- batchnorm: 3-stage deterministic tree ----------------
__global__ __launch_bounds__(256) void bn_stats(const float* __restrict__ H,
                                                float* __restrict__ partial) {
  int tid = threadIdx.x;
  int c4 = (tid & 31) * 4;
  int r0 = blockIdx.x * 32 + (tid >> 5) * 4;
  float s0 = 0, s1 = 0, s2 = 0, s3 = 0, q0 = 0, q1 = 0, q2 = 0, q3 = 0;
#pragma unroll
  for (int j = 0; j < 4; ++j) {
    float4 v = *(const float4*)(H + (size_t)(r0 + j) * 128 + c4);
    s0 += v.x; s1 += v.y; s2 += v.z; s3 += v.w;
    q0 += v.x * v.x; q1 += v.y * v.y; q2 += v.z * v.z; q3 += v.w * v.w;
  }
  __shared__ float sh[2][256][4];
  sh[0][tid][0] = s0; sh[0][tid][1] = s1; sh[0][tid][2] = s2; sh[0][tid][3] = s3;
  sh[1][tid][0] = q0; sh[1][tid][1] = q1; sh[1][tid][2] = q2; sh[1][tid][3] = q3;
  __syncthreads();
  if (tid < 32) {
    float a0 = 0, a1 = 0, a2 = 0, a3 = 0, b0 = 0, b1 = 0, b2 = 0, b3 = 0;
#pragma unroll
    for (int g = 0; g < 8; ++g) {
      int u = g * 32 + tid;
      a0 += sh[0][u][0]; a1 += sh[0][u][1]; a2 += sh[0][u][2]; a3 += sh[0][u][3];
      b0 += sh[1][u][0]; b1 += sh[1][u][1]; b2 += sh[1][u][2]; b3 += sh[1][u][3];
    }
    float* p = partial + (size_t)blockIdx.x * 256;
    p[tid * 4 + 0] = a0; p[tid * 4 + 1] = a1; p[tid * 4 + 2] = a2; p[tid * 4 + 3] = a3;
    p[128 + tid * 4 + 0] = b0; p[128 + tid * 4 + 1] = b1;
    p[128 + tid * 4 + 2] = b2; p[128 + tid * 4 + 3] = b3;
  }
}

__global__ __launch_bounds__(256) void bn_reduce(const float* __restrict__ partial,
                                                 float* __restrict__ p2) {
  int tid = threadIdx.x;
  const float* base = partial + (size_t)blockIdx.x * 25 * 256 + tid;
  float a0 = 0, a1 = 0, a2 = 0, a3 = 0, a4 = 0;
#pragma unroll
  for (int j = 0; j < 5; ++j) {
    a0 += base[(j * 5 + 0) * 256];
    a1 += base[(j * 5 + 1) * 256];
    a2 += base[(j * 5 + 2) * 256];
    a3 += base[(j * 5 + 3) * 256];
    a4 += base[(j * 5 + 4) * 256];
  }
  p2[(size_t)blockIdx.x * 256 + tid] = ((a0 + a1) + (a2 + a3)) + a4;
}

__global__ __launch_bounds__(256) void bn_final2(const float* __restrict__ p2,
                                                 const float* __restrict__ gamma,
                                                 const float* __restrict__ beta,
                                                 float* __restrict__ ss) {
  int tid = threadIdx.x;
  double a0 = 0, a1 = 0, a2 = 0, a3 = 0, a4 = 0;
#pragma unroll
  for (int j = 0; j < 5; ++j) {
    a0 += (double)p2[(size_t)(j * 5 + 0) * 256 + tid];
    a1 += (double)p2[(size_t)(j * 5 + 1) * 256 + tid];
    a2 += (double)p2[(size_t)(j * 5 + 2) * 256 + tid];
    a3 += (double)p2[(size_t)(j * 5 + 3) * 256 + tid];
    a4 += (double)p2[(size_t)(j * 5 + 4) * 256 + tid];
  }
  double tot = ((a0 + a1) + (a2 + a3)) + a4;
  __shared__ double sh[256];
  sh[tid] = tot;
  __syncthreads();
  if (tid < 128) {
    double S = sh[tid];
    double Q = sh[128 + tid];
    double mean = S / (double)NN;
    double var = Q / (double)NN - mean * mean;
    float sc = gamma[tid] * rsqrtf((float)var + 1e-5f);
    ss[tid] = sc;
    ss[128 + tid] = beta[tid] - (float)mean * sc;
  }
}

// ---------------- launch ----------------
extern "C" void kernel_launch(void* const* d_in, const int* in_sizes, int n_in,
                              void* d_out, int out_size, void* d_ws, size_t ws_size,
                              hipStream_t stream) {
  const float* x = (const float*)d_in[0];
  const int* ei = (const int*)d_in[1];
  const float* bw0 = (const float*)d_in[2];
  const float* sw0 = (const float*)d_in[3];
  const float* b0 = (const float*)d_in[4];
  const float* bw1 = (const float*)d_in[5];
  const float* sw1 = (const float*)d_in[6];
  const float* b1 = (const float*)d_in[7];
  const float* bwo = (const float*)d_in[8];
  const float* swo = (const float*)d_in[9];
  const float* bo = (const float*)d_in[10];
  const float* gamma = (const float*)d_in[11];
  const float* beta = (const float*)d_in[12];
  const int E = in_sizes[1] / 2;
  const int* esrc = ei;
  const int* edst = ei + E;

  char* ws = (char*)d_ws;
  size_t off = 0;
  auto alloc = [&](size_t bytes) -> void* {
    void* p = ws + off;
    off = (off + bytes + 255) & ~(size_t)255;
    return p;
  };
  // weight packs padded for the ks+2/ks+3 prefetch overrun
  _Float16* WPA0 = (_Float16*)alloc((196608 + 16384) * 2);
  _Float16* WPA1 = (_Float16*)alloc((196608 + 16384) * 2);
  _Float16* WPC = (_Float16*)alloc((65536 + 16384) * 2);
  float* dinv = (float*)alloc(NPAD * 4);  // NPAD so gemm epilogue reads in-bounds
  int* degE = (int*)alloc(NN * 4);
  int* rowptr = (int*)alloc((NN + 1) * 4);
  int* cursor = (int*)alloc(NN * 4);
  int* csr = (int*)alloc((size_t)E * 4);
  _Float16* A = (_Float16*)alloc((size_t)NPAD * 128 * 2);  // fp16 pre-scaled GEMM out
  float* h1 = (float*)alloc((size_t)NN * 128 * 4);         // h2 aliases h1
  float* P0 = (float*)alloc((size_t)NPAD * 64 * 4);
  float* P1 = (float*)alloc((size_t)NPAD * 64 * 4);
  _Float16* Ch = (_Float16*)alloc((size_t)NPAD * 64 * 2);  // fp16 pre-scaled combined out
  float* partial = (float*)alloc((size_t)625 * 256 * 4);
  float* p2 = (float*)alloc((size_t)25 * 256 * 4);
  float* ssb = (float*)alloc(256 * 4);
  float* h2 = h1;
  (void)ws_size; (void)n_in; (void)out_size;

  int egrid = (E + 255) / 256;
  const int GG = 626;  // 626*32 = 20032 rows

  hipMemsetAsync(degE, 0, NN * sizeof(int), stream);
  packw_all<<<1792, 256, 0, stream>>>(bw0, sw0, bw1, sw1, bwo, swo, WPA0, WPA1, WPC);
  count_deg<<<egrid, 256, 0, stream>>>(edst, degE, E);
  build_meta2<<<1, 1024, 0, stream>>>(degE, rowptr, cursor, dinv, NN);
  fill_csr<<<egrid, 256, 0, stream>>>(esrc, edst, cursor, csr, E);

  // layer 0 (+ out chunk 0)
  gemmFA<<<GG, 256, 0, stream>>>(x, ssb, 0, WPA0, dinv, A, P0);
  aggregate128h<<<5000, 256, 0, stream>>>(A, rowptr, csr, dinv, b0, h1);
  bn_stats<<<625, 256, 0, stream>>>(h1, partial);
  bn_reduce<<<25, 256, 0, stream>>>(partial, p2);
  bn_final2<<<1, 256, 0, stream>>>(p2, gamma, beta, ssb);

  // layer 1 (+ out chunk 1)
  gemmFA<<<GG, 256, 0, stream>>>(h1, ssb, 1, WPA1, dinv, A, P1);
  aggregate128h<<<5000, 256, 0, stream>>>(A, rowptr, csr, dinv, b1, h2);
  bn_stats<<<625, 256, 0, stream>>>(h2, partial);
  bn_reduce<<<25, 256, 0, stream>>>(partial, p2);
  bn_final2<<<1, 256, 0, stream>>>(p2, gamma, beta, ssb);

  // out chunk 2 + combine (fused), then aggregate
  gemmFC<<<GG, 256, 0, stream>>>(h2, ssb, WPC, P0, P1, dinv, Ch);
  aggregate40h<<<5000, 256, 0, stream>>>(Ch, rowptr, csr, dinv, bo, (float*)d_out);
}

// Round 10
// 248.017 us; speedup vs baseline: 2.0636x; 1.0080x over previous
//
#include <hip/hip_runtime.h>

#define NN 20000

typedef _Float16 half8 __attribute__((ext_vector_type(8)));
typedef _Float16 half2v __attribute__((ext_vector_type(2)));
typedef float floatx4 __attribute__((ext_vector_type(4)));

#define MFMA16(a, b, c) __builtin_amdgcn_mfma_f32_16x16x32_f16((a), (b), (c), 0, 0, 0)
#define LD8(p) (*(const half8*)(p))
#define SBAR() __builtin_amdgcn_sched_barrier(0)

// ---------------- closed-form cubic B-spline basis (knots -2.5+0.5k) ----------------
// Only 4 of 7 bases nonzero: for x in cell c = floor((x+2.5)*2), active i = c-3..c with
// standard uniform cubic weights. Select-chain placement (static indices only).
__device__ __forceinline__ void bspline7_fast(float x, float b[7]) {
  float u = (x + 2.5f) * 2.0f;
  float cf = floorf(u);
  int c = (int)cf;
  float t = u - cf;
  float omt = 1.0f - t;
  float t2 = t * t, t3 = t2 * t;
  float w0 = omt * omt * omt * (1.0f / 6.0f);              // i = c-3
  float w1 = (3.0f * t3 - 6.0f * t2 + 4.0f) * (1.0f / 6.0f);  // i = c-2
  float w2 = (-3.0f * t3 + 3.0f * t2 + 3.0f * t + 1.0f) * (1.0f / 6.0f);  // i = c-1
  float w3 = t3 * (1.0f / 6.0f);                           // i = c
  bool valid = (c >= 0) && (c <= 9);
#pragma unroll
  for (int i = 0; i < 7; ++i) {
    int d = c - i;
    float w = (d == 0) ? w3 : (d == 1) ? w2 : (d == 2) ? w1 : (d == 3) ? w0 : 0.0f;
    b[i] = valid ? w : 0.0f;
  }
}

__device__ __forceinline__ float silu_f(float x) {
  return x * (1.0f / (1.0f + __expf(-x)));
}

// Build 16 rows of fp16 features into LDS. Layout: Fs[r][chunk][j], chunk = i ^ (r&7).
__device__ __forceinline__ void build_lds16(const float* __restrict__ X,
                                            const float* __restrict__ ss, int has_bn,
                                            int row0, int tid, _Float16* __restrict__ Fs) {
#pragma unroll
  for (int it = 0; it < 8; ++it) {
    int idx = it * 256 + tid;
    int r = idx >> 7, i = idx & 127;
    float xv = X[(size_t)(row0 + r) * 128 + i];
    if (has_bn) xv = xv * ss[i] + ss[128 + i];
    float b[7];
    bspline7_fast(xv, b);
    half8 hv;
    hv[0] = (_Float16)silu_f(xv);
#pragma unroll
    for (int k = 0; k < 7; ++k) hv[k + 1] = (_Float16)b[k];
    *(half8*)(Fs + ((size_t)r * 128 + (i ^ (r & 7))) * 8) = hv;
  }
}

// ---------------- merged weight pack (MFMA B-fragment order) ----------------
__global__ void packw_all(const float* __restrict__ Wb0, const float* __restrict__ Ws0,
                          const float* __restrict__ Wb1, const float* __restrict__ Ws1,
                          const float* __restrict__ WbO, const float* __restrict__ WsO,
                          _Float16* __restrict__ WPA0, _Float16* __restrict__ WPA1,
                          _Float16* __restrict__ WPC) {
  int bid = blockIdx.x;
  if (bid < 1536) {
    int s = (bid >= 768) ? 1 : 0;
    int idx = (bid - s * 768) * 256 + threadIdx.x;  // 196608
    if (idx >= 196608) return;
    const float* Wb = s ? Wb1 : Wb0;
    const float* Wsp = s ? Ws1 : Ws0;
    _Float16* WP = s ? WPA1 : WPA0;
    int jj = idx & 7;
    int lane = (idx >> 3) & 63;
    int u = idx >> 9;  // ks*12 + cb
    int cb = u % 12, ks = u / 12;
    int i = ks * 4 + (lane >> 4);
    int orow = lane & 15;
    float v = 0.0f;
    if (cb < 8) {
      int o = cb * 16 + orow;
      v = (jj == 0) ? Wb[(size_t)o * 128 + i] : Wsp[(size_t)o * 896 + i * 7 + (jj - 1)];
    } else {
      int o = (cb - 8) * 16 + orow;
      if (o < 40)
        v = (jj == 0) ? WbO[(size_t)o * 384 + s * 128 + i]
                      : WsO[(size_t)o * 2688 + s * 896 + i * 7 + (jj - 1)];
    }
    WP[idx] = (_Float16)v;
  } else {
    int idx = (bid - 1536) * 256 + threadIdx.x;  // 65536
    if (idx >= 65536) return;
    int jj = idx & 7;
    int lane = (idx >> 3) & 63;
    int u = idx >> 9;
    int cb = u & 3, ks = u >> 2;
    int i = ks * 4 + (lane >> 4);
    int o = cb * 16 + (lane & 15);
    float v = 0.0f;
    if (o < 40)
      v = (jj == 0) ? WbO[(size_t)o * 384 + 2 * 128 + i]
                    : WsO[(size_t)o * 2688 + 2 * 896 + i * 7 + (jj - 1)];
    WPC[idx] = (_Float16)v;
  }
}

// ---------------- graph meta ----------------
__global__ void count_deg(const int* __restrict__ dst, int* __restrict__ degE, int E) {
  int e = blockIdx.x * 256 + threadIdx.x;
  if (e < E) atomicAdd(&degE[dst[e]], 1);
}

__global__ void build_meta2(const int* __restrict__ degE, int* __restrict__ rowptr,
                            int* __restrict__ cursor, float* __restrict__ dinv, int n) {
  __shared__ int wsum[16];
  int tid = threadIdx.x, lane = tid & 63, wid = tid >> 6;
  int i0 = tid * 20;
  int d[20];
  int s = 0;
#pragma unroll
  for (int j = 0; j < 20; ++j) {
    int i = i0 + j;
    int v = (i < n) ? degE[i] : 0;
    d[j] = v;
    s += v;
    if (i < n) dinv[i] = rsqrtf((float)(v + 1));  // +1 self loop
  }
  int val = s;
#pragma unroll
  for (int off = 1; off < 64; off <<= 1) {
    int t = __shfl_up(val, off);
    if (lane >= off) val += t;
  }
  if (lane == 63) wsum[wid] = val;
  __syncthreads();
  if (wid == 0) {
    int wv = (lane < 16) ? wsum[lane] : 0;
#pragma unroll
    for (int off = 1; off < 16; off <<= 1) {
      int t = __shfl_up(wv, off);
      if (lane >= off) wv += t;
    }
    if (lane < 16) wsum[lane] = wv;
  }
  __syncthreads();
  int base = (wid ? wsum[wid - 1] : 0) + val - s;
  if (tid == 0) rowptr[0] = 0;
#pragma unroll
  for (int j = 0; j < 20; ++j) {
    int i = i0 + j;
    if (i < n) {
      cursor[i] = base;
      rowptr[i + 1] = base + d[j];
      base += d[j];
    }
  }
}

__global__ void fill_csr(const int* __restrict__ src, const int* __restrict__ dst,
                         int* __restrict__ cursor, int* __restrict__ csr, int E) {
  int e = blockIdx.x * 256 + threadIdx.x;
  if (e < E) {
    int p = atomicAdd(&cursor[dst[e]], 1);
    csr[p] = src[e];
  }
}

// ---------------- fused KAN GEMM: BM=16, 32KB LDS, 4 waves x 3 cb ----------------
__global__ __launch_bounds__(256) void gemmFA(const float* __restrict__ X,
                                              const float* __restrict__ ss, int has_bn,
                                              const _Float16* __restrict__ WP,
                                              const float* __restrict__ dinv,
                                              _Float16* __restrict__ A, float* __restrict__ P) {
  __shared__ _Float16 Fs[16 * 1024];  // 32 KB
  int tid = threadIdx.x;
  int lane = tid & 63, cg = tid >> 6;
  int row0 = blockIdx.x * 16;
  build_lds16(X, ss, has_bn, row0, tid, Fs);
  __syncthreads();
  int rx = lane & 7, kg = lane >> 4;
  const _Float16* Fr = Fs + (size_t)(lane & 15) * 1024;
  const _Float16* Bp = WP + ((size_t)(cg * 3) * 64 + lane) * 8;
  floatx4 acc0 = {}, acc1 = {}, acc2 = {};
  half8 xb0 = LD8(Bp), xb1 = LD8(Bp + 512), xb2 = LD8(Bp + 1024);
  half8 yb0 = LD8(Bp + 6144), yb1 = LD8(Bp + 6144 + 512), yb2 = LD8(Bp + 6144 + 1024);
#pragma unroll 1
  for (int ks = 0; ks < 32; ks += 2) {
    half8 a0 = LD8(Fr + (size_t)((ks * 4 + kg) ^ rx) * 8);
    SBAR();
    acc0 = MFMA16(a0, xb0, acc0);
    acc1 = MFMA16(a0, xb1, acc1);
    acc2 = MFMA16(a0, xb2, acc2);
    SBAR();
    {  // B for ks+2 (pad covers overrun)
      const _Float16* bn = Bp + (size_t)(ks + 2) * 6144;
      xb0 = LD8(bn); xb1 = LD8(bn + 512); xb2 = LD8(bn + 1024);
    }
    half8 c0 = LD8(Fr + (size_t)(((ks + 1) * 4 + kg) ^ rx) * 8);
    SBAR();
    acc0 = MFMA16(c0, yb0, acc0);
    acc1 = MFMA16(c0, yb1, acc1);
    acc2 = MFMA16(c0, yb2, acc2);
    SBAR();
    {  // B for ks+3
      const _Float16* bn = Bp + (size_t)(ks + 3) * 6144;
      yb0 = LD8(bn); yb1 = LD8(bn + 512); yb2 = LD8(bn + 1024);
    }
    SBAR();
  }
  int oc = lane & 15;
  int r0 = row0 + (lane >> 4) * 4;
  floatx4 accs[3] = {acc0, acc1, acc2};
#pragma unroll
  for (int q = 0; q < 3; ++q) {
    int cb = cg * 3 + q;
    if (cb < 8) {
#pragma unroll
      for (int t = 0; t < 4; ++t)
        A[(size_t)(r0 + t) * 128 + cb * 16 + oc] = (_Float16)(accs[q][t] * dinv[r0 + t]);
    } else {
#pragma unroll
      for (int t = 0; t < 4; ++t) P[(size_t)(r0 + t) * 64 + (cb - 8) * 16 + oc] = accs[q][t];
    }
  }
}

// fused final chunk: build(h2) + GEMM (4 cb, 1/wave) + P0 + P1, scaled by dinv -> C fp16
__global__ __launch_bounds__(256) void gemmFC(const float* __restrict__ X,
                                              const float* __restrict__ ss,
                                              const _Float16* __restrict__ WP,
                                              const float* __restrict__ P0,
                                              const float* __restrict__ P1,
                                              const float* __restrict__ dinv,
                                              _Float16* __restrict__ C) {
  __shared__ _Float16 Fs[16 * 1024];  // 32 KB
  int tid = threadIdx.x;
  int lane = tid & 63, cg = tid >> 6;
  int row0 = blockIdx.x * 16;
  build_lds16(X, ss, 1, row0, tid, Fs);
  __syncthreads();
  int rx = lane & 7, kg = lane >> 4;
  const _Float16* Fr = Fs + (size_t)(lane & 15) * 1024;
  const _Float16* Bp = WP + ((size_t)cg * 64 + lane) * 8;
  floatx4 acc0 = {};
  half8 xb = LD8(Bp), yb = LD8(Bp + 2048);
#pragma unroll 1
  for (int ks = 0; ks < 32; ks += 2) {
    half8 a0 = LD8(Fr + (size_t)((ks * 4 + kg) ^ rx) * 8);
    SBAR();
    acc0 = MFMA16(a0, xb, acc0);
    SBAR();
    xb = LD8(Bp + (size_t)(ks + 2) * 2048);
    half8 c0 = LD8(Fr + (size_t)(((ks + 1) * 4 + kg) ^ rx) * 8);
    SBAR();
    acc0 = MFMA16(c0, yb, acc0);
    SBAR();
    yb = LD8(Bp + (size_t)(ks + 3) * 2048);
    SBAR();
  }
  int oc = lane & 15;
  int r0 = row0 + (lane >> 4) * 4;
#pragma unroll
  for (int t = 0; t < 4; ++t) {
    size_t idx = (size_t)(r0 + t) * 64 + cg * 16 + oc;
    C[idx] = (_Float16)((acc0[t] + P0[idx] + P1[idx]) * dinv[r0 + t]);
  }
}

// ---------------- aggregation: wave per node, pre-scaled fp16 rows, 4-way ILP ----------------
__global__ __launch_bounds__(256) void aggregate128h(const _Float16* __restrict__ Ah,
                                                     const int* __restrict__ rowptr,
                                                     const int* __restrict__ csr,
                                                     const float* __restrict__ dinv,
                                                     const float* __restrict__ bias,
                                                     float* __restrict__ Y) {
  int wid = threadIdx.x >> 6, lane = threadIdx.x & 63;
  int n = blockIdx.x * 4 + wid;  // grid 5000 -> n < 20000
  float di = dinv[n];
  half2v self = *(const half2v*)(Ah + (size_t)n * 128 + lane * 2);
  float a0 = (float)self[0], a1 = (float)self[1];
  float b0x = 0, b0y = 0, b1x = 0, b1y = 0, b2x = 0, b2y = 0, b3x = 0, b3y = 0;
  int e0 = rowptr[n], m = rowptr[n + 1] - e0;
  int j = 0;
  for (; j + 4 <= m; j += 4) {
    int s0 = csr[e0 + j], s1 = csr[e0 + j + 1], s2 = csr[e0 + j + 2], s3 = csr[e0 + j + 3];
    half2v r0 = *(const half2v*)(Ah + (size_t)s0 * 128 + lane * 2);
    half2v r1 = *(const half2v*)(Ah + (size_t)s1 * 128 + lane * 2);
    half2v r2 = *(const half2v*)(Ah + (size_t)s2 * 128 + lane * 2);
    half2v r3 = *(const half2v*)(Ah + (size_t)s3 * 128 + lane * 2);
    b0x += (float)r0[0]; b0y += (float)r0[1];
    b1x += (float)r1[0]; b1y += (float)r1[1];
    b2x += (float)r2[0]; b2y += (float)r2[1];
    b3x += (float)r3[0]; b3y += (float)r3[1];
  }
  for (; j < m; ++j) {
    int s = csr[e0 + j];
    half2v r = *(const half2v*)(Ah + (size_t)s * 128 + lane * 2);
    b0x += (float)r[0]; b0y += (float)r[1];
  }
  a0 += (b0x + b1x) + (b2x + b3x);
  a1 += (b0y + b1y) + (b2y + b3y);
  float2 outv = {a0 * di + bias[lane * 2], a1 * di + bias[lane * 2 + 1]};
  *(float2*)(Y + (size_t)n * 128 + lane * 2) = outv;
}

__global__ __launch_bounds__(256) void aggregate40h(const _Float16* __restrict__ Ch,
                                                    const int* __restrict__ rowptr,
                                                    const int* __restrict__ csr,
                                                    const float* __restrict__ dinv,
                                                    const float* __restrict__ bias,
                                                    float* __restrict__ out) {
  int wid = threadIdx.x >> 6, lane = threadIdx.x & 63;
  int n = blockIdx.x * 4 + wid;
  float di = dinv[n];
  float a = (float)Ch[(size_t)n * 64 + lane];
  float b0 = 0, b1 = 0, b2 = 0, b3 = 0;
  int e0 = rowptr[n], m = rowptr[n + 1] - e0;
  int j = 0;
  for (; j + 4 <= m; j += 4) {
    int s0 = csr[e0 + j], s1 = csr[e0 + j + 1], s2 = csr[e0 + j + 2], s3 = csr[e0 + j + 3];
    b0 += (float)Ch[(size_t)s0 * 64 + lane];
    b1 += (float)Ch[(size_t)s1 * 64 + lane];
    b2 += (float)Ch[(size_t)s2 * 64 + lane];
    b3 += (float)Ch[(size_t)s3 * 64 + lane];
  }
  for (; j < m; ++j) {
    int s = csr[e0 + j];
    b0 += (float)Ch[(size_t)s * 64 + lane];
  }
  a += (b0 + b1) + (b2 + b3);
  if (lane < 40) out[(size_t)n * 40 + lane] = a * di + bias[lane];
}

// ---------------- batchnorm: 3-stage deterministic tree ----------------
__global__ __launch_bounds__(256) void bn_stats(const float* __restrict__ H,
                                                float* __restrict__ partial) {
  int tid = threadIdx.x;
  int c4 = (tid & 31) * 4;
  int r0 = blockIdx.x * 32 + (tid >> 5) * 4;
  float s0 = 0, s1 = 0, s2 = 0, s3 = 0, q0 = 0, q1 = 0, q2 = 0, q3 = 0;
#pragma unroll
  for (int j = 0; j < 4; ++j) {
    float4 v = *(const float4*)(H + (size_t)(r0 + j) * 128 + c4);
    s0 += v.x; s1 += v.y; s2 += v.z; s3 += v.w;
    q0 += v.x * v.x; q1 += v.y * v.y; q2 += v.z * v.z; q3 += v.w * v.w;
  }
  __shared__ float sh[2][256][4];
  sh[0][tid][0] = s0; sh[0][tid][1] = s1; sh[0][tid][2] = s2; sh[0][tid][3] = s3;
  sh[1][tid][0] = q0; sh[1][tid][1] = q1; sh[1][tid][2] = q2; sh[1][tid][3] = q3;
  __syncthreads();
  if (tid < 32) {
    float a0 = 0, a1 = 0, a2 = 0, a3 = 0, b0 = 0, b1 = 0, b2 = 0, b3 = 0;
#pragma unroll
    for (int g = 0; g < 8; ++g) {
      int u = g * 32 + tid;
      a0 += sh[0][u][0]; a1 += sh[0][u][1]; a2 += sh[0][u][2]; a3 += sh[0][u][3];
      b0 += sh[1][u][0]; b1 += sh[1][u][1]; b2 += sh[1][u][2]; b3 += sh[1][u][3];
    }
    float* p = partial + (size_t)blockIdx.x * 256;
    p[tid * 4 + 0] = a0; p[tid * 4 + 1] = a1; p[tid * 4 + 2] = a2; p[tid * 4 + 3] = a3;
    p[128 + tid * 4 + 0] = b0; p[128 + tid * 4 + 1] = b1;
    p[128 + tid * 4 + 2] = b2; p[128 + tid * 4 + 3] = b3;
  }
}

__global__ __launch_bounds__(256) void bn_reduce(const float* __restrict__ partial,
                                                 float* __restrict__ p2) {
  int tid = threadIdx.x;
  const float* base = partial + (size_t)blockIdx.x * 25 * 256 + tid;
  float a0 = 0, a1 = 0, a2 = 0, a3 = 0, a4 = 0;
#pragma unroll
  for (int j = 0; j < 5; ++j) {
    a0 += base[(j * 5 + 0) * 256];
    a1 += base[(j * 5 + 1) * 256];
    a2 += base[(j * 5 + 2) * 256];
    a3 += base[(j * 5 + 3) * 256];
    a4 += base[(j * 5 + 4) * 256];
  }
  p2[(size_t)blockIdx.x * 256 + tid] = ((a0 + a1) + (a2 + a3)) + a4;
}

__global__ __launch_bounds__(256) void bn_final2(const float* __restrict__ p2,
                                                 const float* __restrict__ gamma,
                                                 const float* __restrict__ beta,
                                                 float* __restrict__ ss) {
  int tid = threadIdx.x;
  double a0 = 0, a1 = 0, a2 = 0, a3 = 0, a4 = 0;
#pragma unroll
  for (int j = 0; j < 5; ++j) {
    a0 += (double)p2[(size_t)(j * 5 + 0) * 256 + tid];
    a1 += (double)p2[(size_t)(j * 5 + 1) * 256 + tid];
    a2 += (double)p2[(size_t)(j * 5 + 2) * 256 + tid];
    a3 += (double)p2[(size_t)(j * 5 + 3) * 256 + tid];
    a4 += (double)p2[(size_t)(j * 5 + 4) * 256 + tid];
  }
  double tot = ((a0 + a1) + (a2 + a3)) + a4;
  __shared__ double sh[256];
  sh[tid] = tot;
  __syncthreads();
  if (tid < 128) {
    double S = sh[tid];
    double Q = sh[128 + tid];
    double mean = S / (double)NN;
    double var = Q / (double)NN - mean * mean;
    float sc = gamma[tid] * rsqrtf((float)var + 1e-5f);
    ss[tid] = sc;
    ss[128 + tid] = beta[tid] - (float)mean * sc;
  }
}

// ---------------- launch ----------------
extern "C" void kernel_launch(void* const* d_in, const int* in_sizes, int n_in,
                              void* d_out, int out_size, void* d_ws, size_t ws_size,
                              hipStream_t stream) {
  const float* x = (const float*)d_in[0];
  const int* ei = (const int*)d_in[1];
  const float* bw0 = (const float*)d_in[2];
  const float* sw0 = (const float*)d_in[3];
  const float* b0 = (const float*)d_in[4];
  const float* bw1 = (const float*)d_in[5];
  const float* sw1 = (const float*)d_in[6];
  const float* b1 = (const float*)d_in[7];
  const float* bwo = (const float*)d_in[8];
  const float* swo = (const float*)d_in[9];
  const float* bo = (const float*)d_in[10];
  const float* gamma = (const float*)d_in[11];
  const float* beta = (const float*)d_in[12];
  const int E = in_sizes[1] / 2;
  const int* esrc = ei;
  const int* edst = ei + E;

  char* ws = (char*)d_ws;
  size_t off = 0;
  auto alloc = [&](size_t bytes) -> void* {
    void* p = ws + off;
    off = (off + bytes + 255) & ~(size_t)255;
    return p;
  };
  // weight packs padded for the ks+2/ks+3 prefetch overrun
  _Float16* WPA0 = (_Float16*)alloc((196608 + 16384) * 2);
  _Float16* WPA1 = (_Float16*)alloc((196608 + 16384) * 2);
  _Float16* WPC = (_Float16*)alloc((65536 + 16384) * 2);
  float* dinv = (float*)alloc(NN * 4);
  int* degE = (int*)alloc(NN * 4);
  int* rowptr = (int*)alloc((NN + 1) * 4);
  int* cursor = (int*)alloc(NN * 4);
  int* csr = (int*)alloc((size_t)E * 4);
  _Float16* A = (_Float16*)alloc((size_t)NN * 128 * 2);  // fp16 pre-scaled GEMM out
  float* h1 = (float*)alloc((size_t)NN * 128 * 4);       // h2 aliases h1
  float* P0 = (float*)alloc((size_t)NN * 64 * 4);
  float* P1 = (float*)alloc((size_t)NN * 64 * 4);
  _Float16* Ch = (_Float16*)alloc((size_t)NN * 64 * 2);  // fp16 pre-scaled combined out
  float* partial = (float*)alloc((size_t)625 * 256 * 4);
  float* p2 = (float*)alloc((size_t)25 * 256 * 4);
  float* ssb = (float*)alloc(256 * 4);
  float* h2 = h1;
  (void)ws_size; (void)n_in; (void)out_size;

  int egrid = (E + 255) / 256;
  const int GG = 1250;  // 1250*16 = 20000 exactly

  hipMemsetAsync(degE, 0, NN * sizeof(int), stream);
  packw_all<<<1792, 256, 0, stream>>>(bw0, sw0, bw1, sw1, bwo, swo, WPA0, WPA1, WPC);
  count_deg<<<egrid, 256, 0, stream>>>(edst, degE, E);
  build_meta2<<<1, 1024, 0, stream>>>(degE, rowptr, cursor, dinv, NN);
  fill_csr<<<egrid, 256, 0, stream>>>(esrc, edst, cursor, csr, E);

  // layer 0 (+ out chunk 0)
  gemmFA<<<GG, 256, 0, stream>>>(x, ssb, 0, WPA0, dinv, A, P0);
  aggregate128h<<<5000, 256, 0, stream>>>(A, rowptr, csr, dinv, b0, h1);
  bn_stats<<<625, 256, 0, stream>>>(h1, partial);
  bn_reduce<<<25, 256, 0, stream>>>(partial, p2);
  bn_final2<<<1, 256, 0, stream>>>(p2, gamma, beta, ssb);

  // layer 1 (+ out chunk 1)
  gemmFA<<<GG, 256, 0, stream>>>(h1, ssb, 1, WPA1, dinv, A, P1);
  aggregate128h<<<5000, 256, 0, stream>>>(A, rowptr, csr, dinv, b1, h2);
  bn_stats<<<625, 256, 0, stream>>>(h2, partial);
  bn_reduce<<<25, 256, 0, stream>>>(partial, p2);
  bn_final2<<<1, 256, 0, stream>>>(p2, gamma, beta, ssb);

  // out chunk 2 + combine (fused), then aggregate
  gemmFC<<<GG, 256, 0, stream>>>(h2, ssb, WPC, P0, P1, dinv, Ch);
  aggregate40h<<<5000, 256, 0, stream>>>(Ch, rowptr, csr, dinv, bo, (float*)d_out);
}

// Round 11
// 243.122 us; speedup vs baseline: 2.1051x; 1.0201x over previous
//
#include <hip/hip_runtime.h>

#define NN 20000

typedef _Float16 half8 __attribute__((ext_vector_type(8)));
typedef _Float16 half2v __attribute__((ext_vector_type(2)));
typedef float floatx4 __attribute__((ext_vector_type(4)));

#define MFMA16(a, b, c) __builtin_amdgcn_mfma_f32_16x16x32_f16((a), (b), (c), 0, 0, 0)
#define LD8(p) (*(const half8*)(p))
#define SBAR() __builtin_amdgcn_sched_barrier(0)

// ---------------- closed-form cubic B-spline basis (knots -2.5+0.5k) ----------------
__device__ __forceinline__ void bspline7_fast(float x, float b[7]) {
  float u = (x + 2.5f) * 2.0f;
  float cf = floorf(u);
  int c = (int)cf;
  float t = u - cf;
  float omt = 1.0f - t;
  float t2 = t * t, t3 = t2 * t;
  float w0 = omt * omt * omt * (1.0f / 6.0f);
  float w1 = (3.0f * t3 - 6.0f * t2 + 4.0f) * (1.0f / 6.0f);
  float w2 = (-3.0f * t3 + 3.0f * t2 + 3.0f * t + 1.0f) * (1.0f / 6.0f);
  float w3 = t3 * (1.0f / 6.0f);
  bool valid = (c >= 0) && (c <= 9);
#pragma unroll
  for (int i = 0; i < 7; ++i) {
    int d = c - i;
    float w = (d == 0) ? w3 : (d == 1) ? w2 : (d == 2) ? w1 : (d == 3) ? w0 : 0.0f;
    b[i] = valid ? w : 0.0f;
  }
}

__device__ __forceinline__ float silu_f(float x) {
  return x * (1.0f / (1.0f + __expf(-x)));
}

// Build 16 rows of fp16 features into LDS. Layout: Fs[r][chunk][j], chunk = i ^ (r&7).
__device__ __forceinline__ void build_lds16(const float* __restrict__ X,
                                            const float* __restrict__ ss, int has_bn,
                                            int row0, int tid, _Float16* __restrict__ Fs) {
#pragma unroll
  for (int it = 0; it < 8; ++it) {
    int idx = it * 256 + tid;
    int r = idx >> 7, i = idx & 127;
    float xv = X[(size_t)(row0 + r) * 128 + i];
    if (has_bn) xv = xv * ss[i] + ss[128 + i];
    float b[7];
    bspline7_fast(xv, b);
    half8 hv;
    hv[0] = (_Float16)silu_f(xv);
#pragma unroll
    for (int k = 0; k < 7; ++k) hv[k + 1] = (_Float16)b[k];
    *(half8*)(Fs + ((size_t)r * 128 + (i ^ (r & 7))) * 8) = hv;
  }
}

// ---------------- merged weight pack (MFMA B-fragment order) ----------------
__global__ void packw_all(const float* __restrict__ Wb0, const float* __restrict__ Ws0,
                          const float* __restrict__ Wb1, const float* __restrict__ Ws1,
                          const float* __restrict__ WbO, const float* __restrict__ WsO,
                          _Float16* __restrict__ WPA0, _Float16* __restrict__ WPA1,
                          _Float16* __restrict__ WPC) {
  int bid = blockIdx.x;
  if (bid < 1536) {
    int s = (bid >= 768) ? 1 : 0;
    int idx = (bid - s * 768) * 256 + threadIdx.x;  // 196608
    if (idx >= 196608) return;
    const float* Wb = s ? Wb1 : Wb0;
    const float* Wsp = s ? Ws1 : Ws0;
    _Float16* WP = s ? WPA1 : WPA0;
    int jj = idx & 7;
    int lane = (idx >> 3) & 63;
    int u = idx >> 9;  // ks*12 + cb
    int cb = u % 12, ks = u / 12;
    int i = ks * 4 + (lane >> 4);
    int orow = lane & 15;
    float v = 0.0f;
    if (cb < 8) {
      int o = cb * 16 + orow;
      v = (jj == 0) ? Wb[(size_t)o * 128 + i] : Wsp[(size_t)o * 896 + i * 7 + (jj - 1)];
    } else {
      int o = (cb - 8) * 16 + orow;
      if (o < 40)
        v = (jj == 0) ? WbO[(size_t)o * 384 + s * 128 + i]
                      : WsO[(size_t)o * 2688 + s * 896 + i * 7 + (jj - 1)];
    }
    WP[idx] = (_Float16)v;
  } else {
    int idx = (bid - 1536) * 256 + threadIdx.x;  // 65536
    if (idx >= 65536) return;
    int jj = idx & 7;
    int lane = (idx >> 3) & 63;
    int u = idx >> 9;
    int cb = u & 3, ks = u >> 2;
    int i = ks * 4 + (lane >> 4);
    int o = cb * 16 + (lane & 15);
    float v = 0.0f;
    if (o < 40)
      v = (jj == 0) ? WbO[(size_t)o * 384 + 2 * 128 + i]
                    : WsO[(size_t)o * 2688 + 2 * 896 + i * 7 + (jj - 1)];
    WPC[idx] = (_Float16)v;
  }
}

// ---------------- graph meta ----------------
__global__ void count_deg(const int* __restrict__ dst, int* __restrict__ degE, int E) {
  int e = blockIdx.x * 256 + threadIdx.x;
  if (e < E) atomicAdd(&degE[dst[e]], 1);
}

__global__ void build_meta2(const int* __restrict__ degE, int* __restrict__ rowptr,
                            int* __restrict__ cursor, float* __restrict__ dinv, int n) {
  __shared__ int wsum[16];
  int tid = threadIdx.x, lane = tid & 63, wid = tid >> 6;
  int i0 = tid * 20;
  int d[20];
  int s = 0;
#pragma unroll
  for (int j = 0; j < 20; ++j) {
    int i = i0 + j;
    int v = (i < n) ? degE[i] : 0;
    d[j] = v;
    s += v;
    if (i < n) dinv[i] = rsqrtf((float)(v + 1));  // +1 self loop
  }
  int val = s;
#pragma unroll
  for (int off = 1; off < 64; off <<= 1) {
    int t = __shfl_up(val, off);
    if (lane >= off) val += t;
  }
  if (lane == 63) wsum[wid] = val;
  __syncthreads();
  if (wid == 0) {
    int wv = (lane < 16) ? wsum[lane] : 0;
#pragma unroll
    for (int off = 1; off < 16; off <<= 1) {
      int t = __shfl_up(wv, off);
      if (lane >= off) wv += t;
    }
    if (lane < 16) wsum[lane] = wv;
  }
  __syncthreads();
  int base = (wid ? wsum[wid - 1] : 0) + val - s;
  if (tid == 0) rowptr[0] = 0;
#pragma unroll
  for (int j = 0; j < 20; ++j) {
    int i = i0 + j;
    if (i < n) {
      cursor[i] = base;
      rowptr[i + 1] = base + d[j];
      base += d[j];
    }
  }
}

__global__ void fill_csr(const int* __restrict__ src, const int* __restrict__ dst,
                         int* __restrict__ cursor, int* __restrict__ csr, int E) {
  int e = blockIdx.x * 256 + threadIdx.x;
  if (e < E) {
    int p = atomicAdd(&cursor[dst[e]], 1);
    csr[p] = src[e];
  }
}

// ---------------- fused KAN GEMM: BM=16, depth-4 A+B pipeline ----------------
// 256 thr = 4 waves x 3 cb. Sets S0..S3 hold {A-frag, 3 B-frags} for ks..ks+3.
__global__ __launch_bounds__(256) void gemmFA(const float* __restrict__ X,
                                              const float* __restrict__ ss, int has_bn,
                                              const _Float16* __restrict__ WP,
                                              const float* __restrict__ dinv,
                                              _Float16* __restrict__ A, float* __restrict__ P) {
  __shared__ _Float16 Fs[16 * 1024];  // 32 KB
  int tid = threadIdx.x;
  int lane = tid & 63, cg = tid >> 6;
  int row0 = blockIdx.x * 16;
  build_lds16(X, ss, has_bn, row0, tid, Fs);
  __syncthreads();
  int rx = lane & 7, kg = lane >> 4;
  const _Float16* Fr = Fs + (size_t)(lane & 15) * 1024;
  const _Float16* Bp = WP + ((size_t)(cg * 3) * 64 + lane) * 8;
  floatx4 acc0 = {}, acc1 = {}, acc2 = {};

#define LDA_F(kk) LD8(Fr + (size_t)((((kk) * 4) + kg) ^ rx) * 8)
#define LDB_F(kk, q) LD8(Bp + (size_t)(kk) * 6144 + (q) * 512)

  half8 a0 = LDA_F(0), b00 = LDB_F(0, 0), b01 = LDB_F(0, 1), b02 = LDB_F(0, 2);
  half8 a1 = LDA_F(1), b10 = LDB_F(1, 0), b11 = LDB_F(1, 1), b12 = LDB_F(1, 2);
  half8 a2 = LDA_F(2), b20 = LDB_F(2, 0), b21 = LDB_F(2, 1), b22 = LDB_F(2, 2);
  half8 a3 = LDA_F(3), b30 = LDB_F(3, 0), b31 = LDB_F(3, 1), b32 = LDB_F(3, 2);

#pragma unroll 1
  for (int ks = 0; ks < 28; ks += 4) {
    SBAR();
    acc0 = MFMA16(a0, b00, acc0);
    acc1 = MFMA16(a0, b01, acc1);
    acc2 = MFMA16(a0, b02, acc2);
    SBAR();
    a0 = LDA_F(ks + 4); b00 = LDB_F(ks + 4, 0); b01 = LDB_F(ks + 4, 1); b02 = LDB_F(ks + 4, 2);
    SBAR();
    acc0 = MFMA16(a1, b10, acc0);
    acc1 = MFMA16(a1, b11, acc1);
    acc2 = MFMA16(a1, b12, acc2);
    SBAR();
    a1 = LDA_F(ks + 5); b10 = LDB_F(ks + 5, 0); b11 = LDB_F(ks + 5, 1); b12 = LDB_F(ks + 5, 2);
    SBAR();
    acc0 = MFMA16(a2, b20, acc0);
    acc1 = MFMA16(a2, b21, acc1);
    acc2 = MFMA16(a2, b22, acc2);
    SBAR();
    a2 = LDA_F(ks + 6); b20 = LDB_F(ks + 6, 0); b21 = LDB_F(ks + 6, 1); b22 = LDB_F(ks + 6, 2);
    SBAR();
    acc0 = MFMA16(a3, b30, acc0);
    acc1 = MFMA16(a3, b31, acc1);
    acc2 = MFMA16(a3, b32, acc2);
    SBAR();
    a3 = LDA_F(ks + 7); b30 = LDB_F(ks + 7, 0); b31 = LDB_F(ks + 7, 1); b32 = LDB_F(ks + 7, 2);
    SBAR();
  }
  // epilogue: ks = 28..31, no prefetch
  SBAR();
  acc0 = MFMA16(a0, b00, acc0);
  acc1 = MFMA16(a0, b01, acc1);
  acc2 = MFMA16(a0, b02, acc2);
  acc0 = MFMA16(a1, b10, acc0);
  acc1 = MFMA16(a1, b11, acc1);
  acc2 = MFMA16(a1, b12, acc2);
  acc0 = MFMA16(a2, b20, acc0);
  acc1 = MFMA16(a2, b21, acc1);
  acc2 = MFMA16(a2, b22, acc2);
  acc0 = MFMA16(a3, b30, acc0);
  acc1 = MFMA16(a3, b31, acc1);
  acc2 = MFMA16(a3, b32, acc2);
#undef LDA_F
#undef LDB_F

  int oc = lane & 15;
  int r0 = row0 + (lane >> 4) * 4;
  floatx4 accs[3] = {acc0, acc1, acc2};
#pragma unroll
  for (int q = 0; q < 3; ++q) {
    int cb = cg * 3 + q;
    if (cb < 8) {
#pragma unroll
      for (int t = 0; t < 4; ++t)
        A[(size_t)(r0 + t) * 128 + cb * 16 + oc] = (_Float16)(accs[q][t] * dinv[r0 + t]);
    } else {
#pragma unroll
      for (int t = 0; t < 4; ++t) P[(size_t)(r0 + t) * 64 + (cb - 8) * 16 + oc] = accs[q][t];
    }
  }
}

// fused final chunk: build(h2) + GEMM (4 cb, 1/wave) + P0 + P1, scaled by dinv -> C fp16
__global__ __launch_bounds__(256) void gemmFC(const float* __restrict__ X,
                                              const float* __restrict__ ss,
                                              const _Float16* __restrict__ WP,
                                              const float* __restrict__ P0,
                                              const float* __restrict__ P1,
                                              const float* __restrict__ dinv,
                                              _Float16* __restrict__ C) {
  __shared__ _Float16 Fs[16 * 1024];  // 32 KB
  int tid = threadIdx.x;
  int lane = tid & 63, cg = tid >> 6;
  int row0 = blockIdx.x * 16;
  build_lds16(X, ss, 1, row0, tid, Fs);
  __syncthreads();
  int rx = lane & 7, kg = lane >> 4;
  const _Float16* Fr = Fs + (size_t)(lane & 15) * 1024;
  const _Float16* Bp = WP + ((size_t)cg * 64 + lane) * 8;
  floatx4 acc0 = {};

#define LDA_F(kk) LD8(Fr + (size_t)((((kk) * 4) + kg) ^ rx) * 8)
#define LDB_F(kk) LD8(Bp + (size_t)(kk) * 2048)

  half8 a0 = LDA_F(0), b0 = LDB_F(0);
  half8 a1 = LDA_F(1), b1 = LDB_F(1);
  half8 a2 = LDA_F(2), b2 = LDB_F(2);
  half8 a3 = LDA_F(3), b3 = LDB_F(3);

#pragma unroll 1
  for (int ks = 0; ks < 28; ks += 4) {
    SBAR();
    acc0 = MFMA16(a0, b0, acc0);
    SBAR();
    a0 = LDA_F(ks + 4); b0 = LDB_F(ks + 4);
    SBAR();
    acc0 = MFMA16(a1, b1, acc0);
    SBAR();
    a1 = LDA_F(ks + 5); b1 = LDB_F(ks + 5);
    SBAR();
    acc0 = MFMA16(a2, b2, acc0);
    SBAR();
    a2 = LDA_F(ks + 6); b2 = LDB_F(ks + 6);
    SBAR();
    acc0 = MFMA16(a3, b3, acc0);
    SBAR();
    a3 = LDA_F(ks + 7); b3 = LDB_F(ks + 7);
    SBAR();
  }
  SBAR();
  acc0 = MFMA16(a0, b0, acc0);
  acc0 = MFMA16(a1, b1, acc0);
  acc0 = MFMA16(a2, b2, acc0);
  acc0 = MFMA16(a3, b3, acc0);
#undef LDA_F
#undef LDB_F

  int oc = lane & 15;
  int r0 = row0 + (lane >> 4) * 4;
#pragma unroll
  for (int t = 0; t < 4; ++t) {
    size_t idx = (size_t)(r0 + t) * 64 + cg * 16 + oc;
    C[idx] = (_Float16)((acc0[t] + P0[idx] + P1[idx]) * dinv[r0 + t]);
  }
}

// ---------------- aggregation: wave per node, pre-scaled fp16 rows, 4-way ILP ----------------
__global__ __launch_bounds__(256) void aggregate128h(const _Float16* __restrict__ Ah,
                                                     const int* __restrict__ rowptr,
                                                     const int* __restrict__ csr,
                                                     const float* __restrict__ dinv,
                                                     const float* __restrict__ bias,
                                                     float* __restrict__ Y) {
  int wid = threadIdx.x >> 6, lane = threadIdx.x & 63;
  int n = blockIdx.x * 4 + wid;  // grid 5000 -> n < 20000
  float di = dinv[n];
  half2v self = *(const half2v*)(Ah + (size_t)n * 128 + lane * 2);
  float a0 = (float)self[0], a1 = (float)self[1];
  float b0x = 0, b0y = 0, b1x = 0, b1y = 0, b2x = 0, b2y = 0, b3x = 0, b3y = 0;
  int e0 = rowptr[n], m = rowptr[n + 1] - e0;
  int j = 0;
  for (; j + 4 <= m; j += 4) {
    int s0 = csr[e0 + j], s1 = csr[e0 + j + 1], s2 = csr[e0 + j + 2], s3 = csr[e0 + j + 3];
    half2v r0 = *(const half2v*)(Ah + (size_t)s0 * 128 + lane * 2);
    half2v r1 = *(const half2v*)(Ah + (size_t)s1 * 128 + lane * 2);
    half2v r2 = *(const half2v*)(Ah + (size_t)s2 * 128 + lane * 2);
    half2v r3 = *(const half2v*)(Ah + (size_t)s3 * 128 + lane * 2);
    b0x += (float)r0[0]; b0y += (float)r0[1];
    b1x += (float)r1[0]; b1y += (float)r1[1];
    b2x += (float)r2[0]; b2y += (float)r2[1];
    b3x += (float)r3[0]; b3y += (float)r3[1];
  }
  for (; j < m; ++j) {
    int s = csr[e0 + j];
    half2v r = *(const half2v*)(Ah + (size_t)s * 128 + lane * 2);
    b0x += (float)r[0]; b0y += (float)r[1];
  }
  a0 += (b0x + b1x) + (b2x + b3x);
  a1 += (b0y + b1y) + (b2y + b3y);
  float2 outv = {a0 * di + bias[lane * 2], a1 * di + bias[lane * 2 + 1]};
  *(float2*)(Y + (size_t)n * 128 + lane * 2) = outv;
}

__global__ __launch_bounds__(256) void aggregate40h(const _Float16* __restrict__ Ch,
                                                    const int* __restrict__ rowptr,
                                                    const int* __restrict__ csr,
                                                    const float* __restrict__ dinv,
                                                    const float* __restrict__ bias,
                                                    float* __restrict__ out) {
  int wid = threadIdx.x >> 6, lane = threadIdx.x & 63;
  int n = blockIdx.x * 4 + wid;
  float di = dinv[n];
  float a = (float)Ch[(size_t)n * 64 + lane];
  float b0 = 0, b1 = 0, b2 = 0, b3 = 0;
  int e0 = rowptr[n], m = rowptr[n + 1] - e0;
  int j = 0;
  for (; j + 4 <= m; j += 4) {
    int s0 = csr[e0 + j], s1 = csr[e0 + j + 1], s2 = csr[e0 + j + 2], s3 = csr[e0 + j + 3];
    b0 += (float)Ch[(size_t)s0 * 64 + lane];
    b1 += (float)Ch[(size_t)s1 * 64 + lane];
    b2 += (float)Ch[(size_t)s2 * 64 + lane];
    b3 += (float)Ch[(size_t)s3 * 64 + lane];
  }
  for (; j < m; ++j) {
    int s = csr[e0 + j];
    b0 += (float)Ch[(size_t)s * 64 + lane];
  }
  a += (b0 + b1) + (b2 + b3);
  if (lane < 40) out[(size_t)n * 40 + lane] = a * di + bias[lane];
}

// ---------------- batchnorm: 3-stage deterministic tree ----------------
__global__ __launch_bounds__(256) void bn_stats(const float* __restrict__ H,
                                                float* __restrict__ partial) {
  int tid = threadIdx.x;
  int c4 = (tid & 31) * 4;
  int r0 = blockIdx.x * 32 + (tid >> 5) * 4;
  float s0 = 0, s1 = 0, s2 = 0, s3 = 0, q0 = 0, q1 = 0, q2 = 0, q3 = 0;
#pragma unroll
  for (int j = 0; j < 4; ++j) {
    float4 v = *(const float4*)(H + (size_t)(r0 + j) * 128 + c4);
    s0 += v.x; s1 += v.y; s2 += v.z; s3 += v.w;
    q0 += v.x * v.x; q1 += v.y * v.y; q2 += v.z * v.z; q3 += v.w * v.w;
  }
  __shared__ float sh[2][256][4];
  sh[0][tid][0] = s0; sh[0][tid][1] = s1; sh[0][tid][2] = s2; sh[0][tid][3] = s3;
  sh[1][tid][0] = q0; sh[1][tid][1] = q1; sh[1][tid][2] = q2; sh[1][tid][3] = q3;
  __syncthreads();
  if (tid < 32) {
    float a0 = 0, a1 = 0, a2 = 0, a3 = 0, b0 = 0, b1 = 0, b2 = 0, b3 = 0;
#pragma unroll
    for (int g = 0; g < 8; ++g) {
      int u = g * 32 + tid;
      a0 += sh[0][u][0]; a1 += sh[0][u][1]; a2 += sh[0][u][2]; a3 += sh[0][u][3];
      b0 += sh[1][u][0]; b1 += sh[1][u][1]; b2 += sh[1][u][2]; b3 += sh[1][u][3];
    }
    float* p = partial + (size_t)blockIdx.x * 256;
    p[tid * 4 + 0] = a0; p[tid * 4 + 1] = a1; p[tid * 4 + 2] = a2; p[tid * 4 + 3] = a3;
    p[128 + tid * 4 + 0] = b0; p[128 + tid * 4 + 1] = b1;
    p[128 + tid * 4 + 2] = b2; p[128 + tid * 4 + 3] = b3;
  }
}

__global__ __launch_bounds__(256) void bn_reduce(const float* __restrict__ partial,
                                                 float* __restrict__ p2) {
  int tid = threadIdx.x;
  const float* base = partial + (size_t)blockIdx.x * 25 * 256 + tid;
  float a0 = 0, a1 = 0, a2 = 0, a3 = 0, a4 = 0;
#pragma unroll
  for (int j = 0; j < 5; ++j) {
    a0 += base[(j * 5 + 0) * 256];
    a1 += base[(j * 5 + 1) * 256];
    a2 += base[(j * 5 + 2) * 256];
    a3 += base[(j * 5 + 3) * 256];
    a4 += base[(j * 5 + 4) * 256];
  }
  p2[(size_t)blockIdx.x * 256 + tid] = ((a0 + a1) + (a2 + a3)) + a4;
}

__global__ __launch_bounds__(256) void bn_final2(const float* __restrict__ p2,
                                                 const float* __restrict__ gamma,
                                                 const float* __restrict__ beta,
                                                 float* __restrict__ ss) {
  int tid = threadIdx.x;
  double a0 = 0, a1 = 0, a2 = 0, a3 = 0, a4 = 0;
#pragma unroll
  for (int j = 0; j < 5; ++j) {
    a0 += (double)p2[(size_t)(j * 5 + 0) * 256 + tid];
    a1 += (double)p2[(size_t)(j * 5 + 1) * 256 + tid];
    a2 += (double)p2[(size_t)(j * 5 + 2) * 256 + tid];
    a3 += (double)p2[(size_t)(j * 5 + 3) * 256 + tid];
    a4 += (double)p2[(size_t)(j * 5 + 4) * 256 + tid];
  }
  double tot = ((a0 + a1) + (a2 + a3)) + a4;
  __shared__ double sh[256];
  sh[tid] = tot;
  __syncthreads();
  if (tid < 128) {
    double S = sh[tid];
    double Q = sh[128 + tid];
    double mean = S / (double)NN;
    double var = Q / (double)NN - mean * mean;
    float sc = gamma[tid] * rsqrtf((float)var + 1e-5f);
    ss[tid] = sc;
    ss[128 + tid] = beta[tid] - (float)mean * sc;
  }
}

// ---------------- launch ----------------
extern "C" void kernel_launch(void* const* d_in, const int* in_sizes, int n_in,
                              void* d_out, int out_size, void* d_ws, size_t ws_size,
                              hipStream_t stream) {
  const float* x = (const float*)d_in[0];
  const int* ei = (const int*)d_in[1];
  const float* bw0 = (const float*)d_in[2];
  const float* sw0 = (const float*)d_in[3];
  const float* b0 = (const float*)d_in[4];
  const float* bw1 = (const float*)d_in[5];
  const float* sw1 = (const float*)d_in[6];
  const float* b1 = (const float*)d_in[7];
  const float* bwo = (const float*)d_in[8];
  const float* swo = (const float*)d_in[9];
  const float* bo = (const float*)d_in[10];
  const float* gamma = (const float*)d_in[11];
  const float* beta = (const float*)d_in[12];
  const int E = in_sizes[1] / 2;
  const int* esrc = ei;
  const int* edst = ei + E;

  char* ws = (char*)d_ws;
  size_t off = 0;
  auto alloc = [&](size_t bytes) -> void* {
    void* p = ws + off;
    off = (off + bytes + 255) & ~(size_t)255;
    return p;
  };
  _Float16* WPA0 = (_Float16*)alloc(196608 * 2);
  _Float16* WPA1 = (_Float16*)alloc(196608 * 2);
  _Float16* WPC = (_Float16*)alloc(65536 * 2);
  float* dinv = (float*)alloc(NN * 4);
  int* degE = (int*)alloc(NN * 4);
  int* rowptr = (int*)alloc((NN + 1) * 4);
  int* cursor = (int*)alloc(NN * 4);
  int* csr = (int*)alloc((size_t)E * 4);
  _Float16* A = (_Float16*)alloc((size_t)NN * 128 * 2);  // fp16 pre-scaled GEMM out
  float* h1 = (float*)alloc((size_t)NN * 128 * 4);       // h2 aliases h1
  float* P0 = (float*)alloc((size_t)NN * 64 * 4);
  float* P1 = (float*)alloc((size_t)NN * 64 * 4);
  _Float16* Ch = (_Float16*)alloc((size_t)NN * 64 * 2);  // fp16 pre-scaled combined out
  float* partial = (float*)alloc((size_t)625 * 256 * 4);
  float* p2 = (float*)alloc((size_t)25 * 256 * 4);
  float* ssb = (float*)alloc(256 * 4);
  float* h2 = h1;
  (void)ws_size; (void)n_in; (void)out_size;

  int egrid = (E + 255) / 256;
  const int GG = 1250;  // 1250*16 = 20000 exactly

  hipMemsetAsync(degE, 0, NN * sizeof(int), stream);
  packw_all<<<1792, 256, 0, stream>>>(bw0, sw0, bw1, sw1, bwo, swo, WPA0, WPA1, WPC);
  count_deg<<<egrid, 256, 0, stream>>>(edst, degE, E);
  build_meta2<<<1, 1024, 0, stream>>>(degE, rowptr, cursor, dinv, NN);
  fill_csr<<<egrid, 256, 0, stream>>>(esrc, edst, cursor, csr, E);

  // layer 0 (+ out chunk 0)
  gemmFA<<<GG, 256, 0, stream>>>(x, ssb, 0, WPA0, dinv, A, P0);
  aggregate128h<<<5000, 256, 0, stream>>>(A, rowptr, csr, dinv, b0, h1);
  bn_stats<<<625, 256, 0, stream>>>(h1, partial);
  bn_reduce<<<25, 256, 0, stream>>>(partial, p2);
  bn_final2<<<1, 256, 0, stream>>>(p2, gamma, beta, ssb);

  // layer 1 (+ out chunk 1)
  gemmFA<<<GG, 256, 0, stream>>>(h1, ssb, 1, WPA1, dinv, A, P1);
  aggregate128h<<<5000, 256, 0, stream>>>(A, rowptr, csr, dinv, b1, h2);
  bn_stats<<<625, 256, 0, stream>>>(h2, partial);
  bn_reduce<<<25, 256, 0, stream>>>(partial, p2);
  bn_final2<<<1, 256, 0, stream>>>(p2, gamma, beta, ssb);

  // out chunk 2 + combine (fused), then aggregate
  gemmFC<<<GG, 256, 0, stream>>>(h2, ssb, WPC, P0, P1, dinv, Ch);
  aggregate40h<<<5000, 256, 0, stream>>>(Ch, rowptr, csr, dinv, bo, (float*)d_out);
}